// Round 13
// baseline (93.156 us; speedup 1.0000x reference)
//
#include <hip/hip_runtime.h>
#include <cstdint>
#include <cstddef>

#pragma clang fp contract(off)

typedef unsigned long long u64;
typedef unsigned int u32;

#define B_IMG 4
#define N_ROI 8192
#define NCLS 80
#define NCOL 81
#define K_NMS 2048
#define MAXOUT 100
#define THR_SCORE 0.05f
#define THR_IOU 0.5f

#define NBIN 4096
#define BIN_OFF 62771u  // (0x3D4CCCCD >> 14): bin of smallest float > 0.05f
#define WPI 8192        // wave-regions per image (1 RoI per region)
#define WCAP 32         // max keys per RoI (hard max 19: sum of softmax <= 1)
#define STGN 4096       // staging capacity per image

// ---------------------------------------------------------------------------
// Kernel 0: zero hist (B*NBIN words). Own kernel: runtime fill path for this
// size costs ~41 us; this is ~1.5 us.
// ---------------------------------------------------------------------------
__global__ __launch_bounds__(256) void k_zero(u32* __restrict__ p, int nwords) {
  int i = blockIdx.x * 256 + threadIdx.x;
  if (i < nwords) p[i] = 0;
}

// ---------------------------------------------------------------------------
// Softmax: bit-exact reference replication (IEEE, contract off, fixed order).
// ---------------------------------------------------------------------------
__device__ __forceinline__ void softmax_row(const float* __restrict__ row, int lane,
                                            float& s0, float& s1) {
  float v0 = row[lane];
  float v1 = (lane < NCOL - 64) ? row[64 + lane] : -1e38f;
  float m = fmaxf(v0, v1);
  for (int o = 32; o; o >>= 1) m = fmaxf(m, __shfl_xor(m, o));
  float e0 = expf(v0 - m);
  float e1 = (lane < NCOL - 64) ? expf(v1 - m) : 0.0f;
  float s = e0 + e1;
  for (int o = 32; o; o >>= 1) s += __shfl_xor(s, o);
  s0 = e0 / s;
  s1 = e1 / s;
}

// ---------------------------------------------------------------------------
// Kernel 1: softmax per RoI (wave per RoI). NO LDS, NO __syncthreads -- each
// wave owns a private 32-slot region (plain stores). Hist atomics issued at
// the very END (fire-and-forget; nothing barriers on them -> no vmcnt stall;
// R12's regression was atomics before __syncthreads, which drains vmcnt(0)).
// ---------------------------------------------------------------------------
__global__ __launch_bounds__(256) void k_score(const float* __restrict__ cls,
                                               u32* __restrict__ blkcnt,
                                               u64* __restrict__ glist,
                                               u32* __restrict__ hist) {
#pragma clang fp contract(off)
  int t = threadIdx.x, wv = t >> 6, lane = t & 63;
  int wid = blockIdx.x * 4 + wv;  // region id = global RoI id
  int b = wid >> 13;
  int n = wid & (N_ROI - 1);

  float s0, s1;
  softmax_row(cls + (size_t)wid * NCOL, lane, s0, s1);
  bool c0 = s0 > THR_SCORE;
  bool c1 = (lane < 16) && (s1 > THR_SCORE);
  u64 b0 = __ballot(c0), b1 = __ballot(c1);
  int cnt = __popcll(b0) + __popcll(b1);
  if (lane == 0) blkcnt[wid] = (u32)cnt;

  u64 lm = (1ull << lane) - 1ull;
  u64* reg = glist + (size_t)wid * WCAP;
  if (c0) {
    u32 pos = (u32)__popcll(b0 & lm);
    if (pos < WCAP) {
      u32 flat = (u32)(n * NCLS + lane);
      reg[pos] = ((u64)__float_as_uint(s0) << 32) | (u32)(~flat);
    }
  }
  if (c1) {
    u32 pos = (u32)__popcll(b0) + (u32)__popcll(b1 & lm);
    if (pos < WCAP) {
      u32 flat = (u32)(n * NCLS + 64 + lane);
      reg[pos] = ((u64)__float_as_uint(s1) << 32) | (u32)(~flat);
    }
  }

  // hist last: no barrier follows, so these never stall the wave
  if (c0) atomicAdd(&hist[(size_t)b * NBIN + ((__float_as_uint(s0) >> 14) - BIN_OFF)], 1u);
  if (c1) atomicAdd(&hist[(size_t)b * NBIN + ((__float_as_uint(s1) >> 14) - BIN_OFF)], 1u);
}

// ---------------------------------------------------------------------------
// Kernel 2: per image -- cutoff bin, per-bin base offsets, kept count from
// the prebuilt hist (16 KB/image read; NO key streaming). Zeroes bincnt.
// ---------------------------------------------------------------------------
__global__ __launch_bounds__(1024) void k_cutbase(const u32* __restrict__ hist,
                                                  u32* __restrict__ cutg,
                                                  u32* __restrict__ binbase,
                                                  u32* __restrict__ bincnt,
                                                  u32* __restrict__ keptT) {
  __shared__ u32 wsum[16];
  __shared__ int best;
  __shared__ u32 cutsh;
  int b = blockIdx.x, t = threadIdx.x;
  int lane = t & 63, wv = t >> 6;
  const u32* gh = hist + (size_t)b * NBIN;
  u32 v0 = gh[t * 4 + 0], v1 = gh[t * 4 + 1], v2 = gh[t * 4 + 2], v3 = gh[t * 4 + 3];
  u32 my = v0 + v1 + v2 + v3;
  u32 inc = my;
  for (int o = 1; o < 64; o <<= 1) {
    u32 x = __shfl_up(inc, o);
    if (lane >= o) inc += x;
  }
  if (lane == 63) wsum[wv] = inc;
  if (t == 0) best = 0;

  // zero bincnt for this image while the scan settles
  u32* bc = bincnt + (size_t)b * NBIN + t * 4;
  bc[0] = 0; bc[1] = 0; bc[2] = 0; bc[3] = 0;
  __syncthreads();

  u32 wpre = 0;
  for (int i = 0; i < wv; ++i) wpre += wsum[i];
  u32 total = 0;
  for (int i = 0; i < 16; ++i) total += wsum[i];
  u32 excl = wpre + (inc - my);  // prefix_excl(bin t*4)

  u32* bb = binbase + (size_t)b * NBIN + t * 4;
  u32 pi = excl;
  pi += v0; bb[0] = total - pi;
  pi += v1; bb[1] = total - pi;
  pi += v2; bb[2] = total - pi;
  pi += v3; bb[3] = total - pi;

  if (total >= K_NMS) {
    u32 lim = total - K_NMS;
    u32 p = excl;
    int cand = -1;
    if (p <= lim) cand = t * 4 + 0; p += v0;
    if (p <= lim) cand = t * 4 + 1; p += v1;
    if (p <= lim) cand = t * 4 + 2; p += v2;
    if (p <= lim) cand = t * 4 + 3; p += v3;
    if (cand >= 0) atomicMax(&best, cand);
  }
  __syncthreads();
  if (t == 0) {
    u32 c = (total >= K_NMS) ? (u32)best : 0u;
    cutsh = c;
    cutg[b] = c;
  }
  __syncthreads();
  u32 c = cutsh;
  if (t == (int)(c >> 2)) {
    u32 pe = excl;
    int r = (int)(c & 3);
    if (r > 0) pe += v0;
    if (r > 1) pe += v1;
    if (r > 2) pe += v2;
    keptT[b] = total - pe;  // count of keys with bin >= cut
  }
}

// ---------------------------------------------------------------------------
// Kernel 3: scatter kept keys into their bin's slot range in staging.
// 256 blocks x 128 wave-regions. Slab loop bounded by max region count.
// ---------------------------------------------------------------------------
__global__ __launch_bounds__(256) void k_scatter(const u32* __restrict__ blkcnt,
                                                 const u64* __restrict__ glist,
                                                 const u32* __restrict__ cutg,
                                                 const u32* __restrict__ binbase,
                                                 u32* __restrict__ bincnt,
                                                 u64* __restrict__ staging) {
  __shared__ u32 lcnt[128];
  __shared__ u32 mshare;
  int blk = blockIdx.x;        // 0..255
  int b = blk >> 6;            // 64 blocks per image
  int r0 = (blk & 63) * 128;   // first region of this block
  int t = threadIdx.x;
  if (t < 128) {
    u32 cc = blkcnt[b * WPI + r0 + t];
    lcnt[t] = (cc > WCAP) ? WCAP : cc;
  }
  __syncthreads();
  if (t == 0) {
    u32 m = 0;
    for (int i = 0; i < 128; ++i) m = (lcnt[i] > m) ? lcnt[i] : m;
    mshare = m;
  }
  __syncthreads();
  u32 mmax = mshare;
  u32 cut = cutg[b];
  int r = t >> 1;        // 256 threads = 128 regions x 2 slots per slab
  int k0 = t & 1;
  u32 cr = lcnt[r];
  const u64* regp = glist + ((size_t)(b * WPI + r0 + r)) * WCAP;
  for (u32 base = 0; base < mmax; base += 2) {
    u32 k = base + k0;
    if (k < cr) {
      u64 key = regp[k];
      u32 bin = (u32)(key >> 46) - BIN_OFF;
      if (bin >= cut) {
        u32 slot = binbase[(size_t)b * NBIN + bin] +
                   atomicAdd(&bincnt[(size_t)b * NBIN + bin], 1u);
        if (slot < STGN) staging[(size_t)b * STGN + slot] = key;
      }
    }
  }
}

// ---------------------------------------------------------------------------
// Kernel 4: exact in-bin rank -> global slot; decode (reference fp32 math
// exactly) into per-slot outputs; slots [T, 2048) zero-filled.
// ---------------------------------------------------------------------------
__global__ __launch_bounds__(256) void k_rankdecode(const u32* __restrict__ keptT,
                                                    const u32* __restrict__ binbase,
                                                    const u32* __restrict__ bincnt,
                                                    const u64* __restrict__ staging,
                                                    const float* __restrict__ props,
                                                    const float* __restrict__ regs,
                                                    const int* __restrict__ pH,
                                                    const int* __restrict__ pW,
                                                    float4* __restrict__ raw4,
                                                    float4* __restrict__ off4,
                                                    float* __restrict__ area,
                                                    float* __restrict__ scoref,
                                                    int* __restrict__ labeli,
                                                    int* __restrict__ flati) {
#pragma clang fp contract(off)
  int p0 = blockIdx.x * 256 + threadIdx.x;  // 0 .. B*STGN-1
  int b = p0 >> 12;
  int i = p0 & (STGN - 1);
  u32 T = keptT[b];
  if (T > STGN) T = STGN;

  if ((u32)i >= T) {
    if ((u32)i < K_NMS) {  // zero-fill empty slot i
      size_t g = (size_t)b * K_NMS + i;
      raw4[g] = make_float4(0.f, 0.f, 0.f, 0.f);
      off4[g] = make_float4(0.f, 0.f, 0.f, 0.f);
      area[g] = 0.f; scoref[g] = -1.0f; labeli[g] = 0; flati[g] = 0;
    }
    return;
  }

  u64 key = staging[(size_t)b * STGN + i];
  u32 bin = (u32)(key >> 46) - BIN_OFF;
  u32 base = binbase[(size_t)b * NBIN + bin];
  u32 cnt = bincnt[(size_t)b * NBIN + bin];
  u32 end = base + cnt;
  if (end > STGN) end = STGN;
  u32 rank = 0;
  for (u32 j = base; j < end; ++j)
    rank += (staging[(size_t)b * STGN + j] > key) ? 1u : 0u;
  u32 gslot = base + rank;
  if (gslot >= K_NMS) return;
  size_t g = (size_t)b * K_NMS + gslot;

  float Hf = (float)pH[0];
  float Wf = (float)pW[0];
  float offc = fmaxf(Hf, Wf) + 1.0f;  // 1334

  u32 flat = ~(u32)(key & 0xFFFFFFFFull);
  float sc = __uint_as_float((u32)(key >> 32));
  int n = (int)(flat / NCLS);
  int c = (int)(flat - (u32)n * NCLS);

  float4 p = ((const float4*)props)[b * N_ROI + n];
  const float4 dl = *(const float4*)(regs + ((size_t)(b * N_ROI + n)) * (NCLS * 4) + c * 4);

  float mr = fabsf(logf(16.0f / 1000.0f));
  float dx = dl.x * 0.1f;
  float dy = dl.y * 0.1f;
  float dw = fminf(fmaxf(dl.z * 0.2f, -mr), mr);
  float dh = fminf(fmaxf(dl.w * 0.2f, -mr), mr);

  float px = (p.x + p.z) * 0.5f;
  float py = (p.y + p.w) * 0.5f;
  float pw = p.z - p.x;
  float ph = p.w - p.y;

  float tx = pw * dx; float gx = px + tx;
  float ty = ph * dy; float gy = py + ty;
  float gw = pw * expf(dw);
  float gh = ph * expf(dh);
  float hx = gw * 0.5f, hy = gh * 0.5f;

  float x1 = fminf(fmaxf(gx - hx, 0.0f), Wf);
  float y1 = fminf(fmaxf(gy - hy, 0.0f), Hf);
  float x2 = fminf(fmaxf(gx + hx, 0.0f), Wf);
  float y2 = fminf(fmaxf(gy + hy, 0.0f), Hf);

  raw4[g] = make_float4(x1, y1, x2, y2);

  float off = (float)c * offc;
  float ox1 = x1 + off, oy1 = y1 + off, ox2 = x2 + off, oy2 = y2 + off;
  off4[g] = make_float4(ox1, oy1, ox2, oy2);
  area[g] = fmaxf(ox2 - ox1, 0.0f) * fmaxf(oy2 - oy1, 0.0f);
  scoref[g] = sc;
  labeli[g] = c;
  flati[g] = (int)flat;
}

// ---------------------------------------------------------------------------
// Kernel 5: suppression bitmask, triangular (words below diagonal written 0).
// ---------------------------------------------------------------------------
__global__ __launch_bounds__(256) void k_mask(const float4* __restrict__ off4,
                                              const float* __restrict__ area,
                                              u64* __restrict__ masks) {
#pragma clang fp contract(off)
  int wave = threadIdx.x >> 6, lane = threadIdx.x & 63;
  int R = blockIdx.x * 4 + wave;  // 0 .. B*K-1
  int b = R >> 11, i = R & (K_NMS - 1);
  const float4* bb = off4 + (size_t)b * K_NMS;
  const float* aa = area + (size_t)b * K_NMS;
  float4 bi = bb[i];
  float ai = aa[i];
  u64 my = 0;
  for (int w = i >> 6; w < 32; ++w) {
    int j = (w << 6) + lane;
    float4 bj = bb[j];
    float lx = fmaxf(bi.x, bj.x);
    float ly = fmaxf(bi.y, bj.y);
    float rx = fminf(bi.z, bj.z);
    float ry = fminf(bi.w, bj.w);
    float ww = fmaxf(rx - lx, 0.0f);
    float hh = fmaxf(ry - ly, 0.0f);
    float inter = ww * hh;
    float uni = (ai + aa[j]) - inter;
    float iou = inter / fmaxf(uni, 1e-6f);
    bool sup = (j > i) && (iou > THR_IOU);
    u64 word = __ballot(sup);
    if (lane == w) my = word;
  }
  if (lane < 32) masks[((size_t)R << 5) + lane] = my;
}

// ---------------------------------------------------------------------------
// Kernel 6: greedy scan, chunked closure + early termination (R9 structure).
// ---------------------------------------------------------------------------
__global__ __launch_bounds__(64, 1) void k_scanout(const u64* __restrict__ masks,
                                                   const u32* __restrict__ keptT,
                                                   const float* __restrict__ scoref,
                                                   const float4* __restrict__ raw4,
                                                   const int* __restrict__ labeli,
                                                   const int* __restrict__ flati,
                                                   float* __restrict__ out) {
  int b = blockIdx.x;
  int lane = threadIdx.x;

  u32 Tc = keptT[b];
  if (Tc > K_NMS) Tc = K_NMS;
  u64 kw = 0;
  if (lane < 32) {
    int rem = (int)Tc - (lane << 6);
    kw = (rem >= 64) ? ~0ull : ((rem > 0) ? ((1ull << rem) - 1ull) : 0ull);
  }

  const u64* mrow = masks + ((size_t)b << 16);  // b * 2048 * 32
  int myw = lane & 31;
  int half = lane >> 5;

  u64 dnext = mrow[((size_t)lane << 5) + 0];

  for (int c = 0; c < 32; ++c) {
    u64 dcur = dnext;
    if (c < 31) dnext = mrow[((size_t)((c + 1) * 64 + lane) << 5) + (c + 1)];

    const u64* rb = mrow + (((size_t)(c * 64 + half * 32)) << 5) + myw;
    u64 r0 = rb[0u << 5],  r1 = rb[1u << 5],  r2 = rb[2u << 5],  r3 = rb[3u << 5];
    u64 r4 = rb[4u << 5],  r5 = rb[5u << 5],  r6 = rb[6u << 5],  r7 = rb[7u << 5];
    u64 r8 = rb[8u << 5],  r9 = rb[9u << 5],  r10 = rb[10u << 5], r11 = rb[11u << 5];
    u64 r12 = rb[12u << 5], r13 = rb[13u << 5], r14 = rb[14u << 5], r15 = rb[15u << 5];
    u64 r16 = rb[16u << 5], r17 = rb[17u << 5], r18 = rb[18u << 5], r19 = rb[19u << 5];
    u64 r20 = rb[20u << 5], r21 = rb[21u << 5], r22 = rb[22u << 5], r23 = rb[23u << 5];
    u64 r24 = rb[24u << 5], r25 = rb[25u << 5], r26 = rb[26u << 5], r27 = rb[27u << 5];
    u64 r28 = rb[28u << 5], r29 = rb[29u << 5], r30 = rb[30u << 5], r31 = rb[31u << 5];
    asm volatile("" : "+v"(r0), "+v"(r1), "+v"(r2), "+v"(r3));
    asm volatile("" : "+v"(r4), "+v"(r5), "+v"(r6), "+v"(r7));
    asm volatile("" : "+v"(r8), "+v"(r9), "+v"(r10), "+v"(r11));
    asm volatile("" : "+v"(r12), "+v"(r13), "+v"(r14), "+v"(r15));
    asm volatile("" : "+v"(r16), "+v"(r17), "+v"(r18), "+v"(r19));
    asm volatile("" : "+v"(r20), "+v"(r21), "+v"(r22), "+v"(r23));
    asm volatile("" : "+v"(r24), "+v"(r25), "+v"(r26), "+v"(r27));
    asm volatile("" : "+v"(r28), "+v"(r29), "+v"(r30), "+v"(r31));

    u32 dlo = (u32)dcur, dhi = (u32)(dcur >> 32);
    u64 kc = ((u64)(u32)__builtin_amdgcn_readlane((int)(u32)(kw >> 32), c) << 32) |
             (u32)__builtin_amdgcn_readlane((int)(u32)kw, c);
#pragma unroll
    for (int d = 0; d < 64; ++d) {
      u64 dg = ((u64)(u32)__builtin_amdgcn_readlane((int)dhi, d) << 32) |
               (u32)__builtin_amdgcn_readlane((int)dlo, d);
      u64 on = (u64)0 - ((kc >> d) & 1ull);
      kc &= ~(dg & on);
    }

    u32 kb = half ? (u32)(kc >> 32) : (u32)kc;
#define ONB(r) ((u64)0 - (u64)((kb >> (r)) & 1u))
    u64 a0 = (r0 & ONB(0)) | (r1 & ONB(1)) | (r2 & ONB(2)) | (r3 & ONB(3)) |
             (r4 & ONB(4)) | (r5 & ONB(5)) | (r6 & ONB(6)) | (r7 & ONB(7));
    u64 a1 = (r8 & ONB(8)) | (r9 & ONB(9)) | (r10 & ONB(10)) | (r11 & ONB(11)) |
             (r12 & ONB(12)) | (r13 & ONB(13)) | (r14 & ONB(14)) | (r15 & ONB(15));
    u64 a2 = (r16 & ONB(16)) | (r17 & ONB(17)) | (r18 & ONB(18)) | (r19 & ONB(19)) |
             (r20 & ONB(20)) | (r21 & ONB(21)) | (r22 & ONB(22)) | (r23 & ONB(23));
    u64 a3 = (r24 & ONB(24)) | (r25 & ONB(25)) | (r26 & ONB(26)) | (r27 & ONB(27)) |
             (r28 & ONB(28)) | (r29 & ONB(29)) | (r30 & ONB(30)) | (r31 & ONB(31));
#undef ONB
    u64 supp = (a0 | a1) | (a2 | a3);
    supp |= __shfl_xor(supp, 32);
    kw &= ~supp;

    int fin = (lane <= c) ? __popcll(kw) : 0;
    for (int o = 32; o; o >>= 1) fin += __shfl_xor(fin, o);
    if (fin >= MAXOUT) break;
  }

  int pc = (lane < 32) ? __popcll(kw) : 0;
  int pre = pc;
  for (int o = 1; o < 64; o <<= 1) {
    int v = __shfl_up(pre, o);
    if (lane >= o) pre += v;
  }
  int excl = pre - pc;
  int total = __shfl(pre, 63);

  float* ob = out;                              // [B,100,4]
  float* os = out + B_IMG * MAXOUT * 4;         // [B,100]
  float* ol = os + B_IMG * MAXOUT;              // [B,100]
  float* oi = ol + B_IMG * MAXOUT;              // [B,100]

  if (lane < 32) {
    u64 w = kw;
    int r = excl;
    while (w) {
      int bit = __ffsll((long long)w) - 1;
      w &= w - 1;
      if (r < MAXOUT) {
        int j = (lane << 6) + bit;
        size_t g = (size_t)b * K_NMS + j;
        float4 bx = raw4[g];
        int o = b * MAXOUT + r;
        ob[o * 4 + 0] = bx.x; ob[o * 4 + 1] = bx.y;
        ob[o * 4 + 2] = bx.z; ob[o * 4 + 3] = bx.w;
        os[o] = scoref[g];
        ol[o] = (float)labeli[g];
        oi[o] = (float)flati[g];
      }
      ++r;
    }
  }
  for (int r = total + lane; r < MAXOUT; r += 64) {
    int o = b * MAXOUT + r;
    ob[o * 4 + 0] = 0.f; ob[o * 4 + 1] = 0.f; ob[o * 4 + 2] = 0.f; ob[o * 4 + 3] = 0.f;
    os[o] = 0.f;
    ol[o] = -1.0f;
    oi[o] = -1.0f;
  }
}

// ---------------------------------------------------------------------------
extern "C" void kernel_launch(void* const* d_in, const int* in_sizes, int n_in,
                              void* d_out, int out_size, void* d_ws, size_t ws_size,
                              hipStream_t stream) {
  const float* cls = (const float*)d_in[0];
  const float* regs = (const float*)d_in[1];
  const float* props = (const float*)d_in[2];
  const int* pH = (const int*)d_in[3];
  const int* pW = (const int*)d_in[4];

  char* ws = (char*)d_ws;
  size_t o = 0;
  u32* hist = (u32*)(ws + o); o += (size_t)B_IMG * NBIN * sizeof(u32);             // 64 KB (k_zero)
  u32* blkcnt = (u32*)(ws + o); o += (size_t)B_IMG * WPI * sizeof(u32);            // 128 KB
  u32* keptT = (u32*)(ws + o); o += 256;
  u32* cutg = (u32*)(ws + o); o += 256;
  u32* binbase = (u32*)(ws + o); o += (size_t)B_IMG * NBIN * sizeof(u32);          // 64 KB
  u32* bincnt = (u32*)(ws + o); o += (size_t)B_IMG * NBIN * sizeof(u32);           // 64 KB (zeroed in k_cutbase)
  u64* glist = (u64*)(ws + o); o += (size_t)B_IMG * WPI * WCAP * sizeof(u64);      // 8 MB
  u64* staging = (u64*)(ws + o); o += (size_t)B_IMG * STGN * sizeof(u64);          // 128 KB
  float4* raw4 = (float4*)(ws + o); o += (size_t)B_IMG * K_NMS * sizeof(float4);
  float4* off4 = (float4*)(ws + o); o += (size_t)B_IMG * K_NMS * sizeof(float4);
  float* area = (float*)(ws + o); o += (size_t)B_IMG * K_NMS * sizeof(float);
  float* scoref = (float*)(ws + o); o += (size_t)B_IMG * K_NMS * sizeof(float);
  int* labeli = (int*)(ws + o); o += (size_t)B_IMG * K_NMS * sizeof(int);
  int* flati = (int*)(ws + o); o += (size_t)B_IMG * K_NMS * sizeof(int);
  u64* masks = (u64*)(ws + o); o += (size_t)B_IMG * K_NMS * 32 * sizeof(u64);      // 2 MB

  int hist_words = B_IMG * NBIN;  // 16384
  k_zero<<<(hist_words + 255) / 256, 256, 0, stream>>>(hist, hist_words);
  k_score<<<B_IMG * WPI / 4, 256, 0, stream>>>(cls, blkcnt, glist, hist);
  k_cutbase<<<B_IMG, 1024, 0, stream>>>(hist, cutg, binbase, bincnt, keptT);
  k_scatter<<<256, 256, 0, stream>>>(blkcnt, glist, cutg, binbase, bincnt, staging);
  k_rankdecode<<<B_IMG * STGN / 256, 256, 0, stream>>>(keptT, binbase, bincnt, staging,
                                                       props, regs, pH, pW,
                                                       raw4, off4, area, scoref, labeli, flati);
  k_mask<<<B_IMG * K_NMS / 4, 256, 0, stream>>>(off4, area, masks);
  k_scanout<<<B_IMG, 64, 0, stream>>>(masks, keptT, scoref, raw4, labeli, flati, (float*)d_out);
}

// Round 14
// 92.923 us; speedup vs baseline: 1.0025x; 1.0025x over previous
//
#include <hip/hip_runtime.h>
#include <cstdint>
#include <cstddef>

#pragma clang fp contract(off)

typedef unsigned long long u64;
typedef unsigned int u32;

#define B_IMG 4
#define N_ROI 8192
#define NCLS 80
#define NCOL 81
#define K_NMS 2048
#define MAXOUT 100
#define THR_SCORE 0.05f
#define THR_IOU 0.5f

#define NBIN 4096
#define BIN_OFF 62771u  // (0x3D4CCCCD >> 14): bin of smallest float > 0.05f
#define WPI 8192        // wave-regions per image (1 RoI per region)
#define WCAP 32         // max keys per RoI (hard max 19: sum of softmax <= 1)
#define STGN 4096       // staging capacity per image

// ---------------------------------------------------------------------------
// Kernel 0: zero hist (B*NBIN words).
// ---------------------------------------------------------------------------
__global__ __launch_bounds__(256) void k_zero(u32* __restrict__ p, int nwords) {
  int i = blockIdx.x * 256 + threadIdx.x;
  if (i < nwords) p[i] = 0;
}

// ---------------------------------------------------------------------------
// Kernel 1: softmax for FOUR RoIs per wave, fully interleaved. Each RoI's
// computation order (max tree, exp, sum tree, div) is bit-identical to the
// reference replication used since R2 -- only ILP is added (4 independent
// dependency chains hide the shfl/exp/div latency that made the 1-RoI/wave
// version latency-bound at ~40us with VALUBusy 17%).
// ---------------------------------------------------------------------------
__global__ __launch_bounds__(256) void k_score(const float* __restrict__ cls,
                                               u32* __restrict__ blkcnt,
                                               u64* __restrict__ glist,
                                               u32* __restrict__ hist) {
#pragma clang fp contract(off)
  int t = threadIdx.x, wv = t >> 6, lane = t & 63;
  int wid0 = (blockIdx.x * 4 + wv) * 4;  // first of 4 RoIs for this wave
  int b = wid0 >> 13;                    // all 4 in same image (4 | 8192)

  // ---- loads for all 4 RoIs issued up front ----
  const float* row0 = cls + (size_t)(wid0 + 0) * NCOL;
  const float* row1 = cls + (size_t)(wid0 + 1) * NCOL;
  const float* row2 = cls + (size_t)(wid0 + 2) * NCOL;
  const float* row3 = cls + (size_t)(wid0 + 3) * NCOL;
  float a0 = row0[lane], a1 = row1[lane], a2 = row2[lane], a3 = row3[lane];
  bool hi = lane < (NCOL - 64);
  float b0 = hi ? row0[64 + lane] : -1e38f;
  float b1 = hi ? row1[64 + lane] : -1e38f;
  float b2 = hi ? row2[64 + lane] : -1e38f;
  float b3 = hi ? row3[64 + lane] : -1e38f;

  // ---- 4 interleaved max trees (order per RoI identical to reference) ----
  float m0 = fmaxf(a0, b0), m1 = fmaxf(a1, b1), m2 = fmaxf(a2, b2), m3 = fmaxf(a3, b3);
#define MAXSTEP(o) \
  m0 = fmaxf(m0, __shfl_xor(m0, o)); m1 = fmaxf(m1, __shfl_xor(m1, o)); \
  m2 = fmaxf(m2, __shfl_xor(m2, o)); m3 = fmaxf(m3, __shfl_xor(m3, o));
  MAXSTEP(32) MAXSTEP(16) MAXSTEP(8) MAXSTEP(4) MAXSTEP(2) MAXSTEP(1)
#undef MAXSTEP

  // ---- 4 interleaved exp + sum trees ----
  float e0 = expf(a0 - m0), e1 = expf(a1 - m1), e2 = expf(a2 - m2), e3 = expf(a3 - m3);
  float f0 = hi ? expf(b0 - m0) : 0.0f;
  float f1 = hi ? expf(b1 - m1) : 0.0f;
  float f2 = hi ? expf(b2 - m2) : 0.0f;
  float f3 = hi ? expf(b3 - m3) : 0.0f;
  float s0 = e0 + f0, s1 = e1 + f1, s2 = e2 + f2, s3 = e3 + f3;
#define SUMSTEP(o) \
  s0 += __shfl_xor(s0, o); s1 += __shfl_xor(s1, o); \
  s2 += __shfl_xor(s2, o); s3 += __shfl_xor(s3, o);
  SUMSTEP(32) SUMSTEP(16) SUMSTEP(8) SUMSTEP(4) SUMSTEP(2) SUMSTEP(1)
#undef SUMSTEP

  float p0 = e0 / s0, p1 = e1 / s1, p2 = e2 / s2, p3 = e3 / s3;  // class=lane
  float q0 = f0 / s0, q1 = f1 / s1, q2 = f2 / s2, q3 = f3 / s3;  // class=64+lane

  // ---- candidate emission per RoI (ballot-offset plain stores) ----
  u64 lm = (1ull << lane) - 1ull;
  bool lo16 = lane < 16;  // class 64+lane valid & non-background for lane<16
  u32 cnt0, cnt1, cnt2, cnt3;

#define EMIT(R, pv, qv, CNT)                                               \
  {                                                                        \
    bool c0 = pv > THR_SCORE;                                              \
    bool c1 = lo16 && (qv > THR_SCORE);                                    \
    u64 B0 = __ballot(c0), B1 = __ballot(c1);                              \
    CNT = (u32)(__popcll(B0) + __popcll(B1));                              \
    int n = (wid0 + R) & (N_ROI - 1);                                      \
    u64* reg = glist + (size_t)(wid0 + R) * WCAP;                          \
    if (c0) {                                                              \
      u32 pos = (u32)__popcll(B0 & lm);                                    \
      if (pos < WCAP) {                                                    \
        u32 flat = (u32)(n * NCLS + lane);                                 \
        reg[pos] = ((u64)__float_as_uint(pv) << 32) | (u32)(~flat);        \
      }                                                                    \
    }                                                                      \
    if (c1) {                                                              \
      u32 pos = (u32)__popcll(B0) + (u32)__popcll(B1 & lm);                \
      if (pos < WCAP) {                                                    \
        u32 flat = (u32)(n * NCLS + 64 + lane);                            \
        reg[pos] = ((u64)__float_as_uint(qv) << 32) | (u32)(~flat);        \
      }                                                                    \
    }                                                                      \
  }

  EMIT(0, p0, q0, cnt0)
  EMIT(1, p1, q1, cnt1)
  EMIT(2, p2, q2, cnt2)
  EMIT(3, p3, q3, cnt3)
#undef EMIT

  if (lane == 0) {
    uint4 v = make_uint4(cnt0, cnt1, cnt2, cnt3);
    *(uint4*)&blkcnt[wid0] = v;  // wid0 % 4 == 0 -> 16B aligned
  }

  // ---- hist atomics last (fire-and-forget) ----
  u32* gh = hist + (size_t)b * NBIN;
  if (p0 > THR_SCORE) atomicAdd(&gh[(__float_as_uint(p0) >> 14) - BIN_OFF], 1u);
  if (p1 > THR_SCORE) atomicAdd(&gh[(__float_as_uint(p1) >> 14) - BIN_OFF], 1u);
  if (p2 > THR_SCORE) atomicAdd(&gh[(__float_as_uint(p2) >> 14) - BIN_OFF], 1u);
  if (p3 > THR_SCORE) atomicAdd(&gh[(__float_as_uint(p3) >> 14) - BIN_OFF], 1u);
  if (lo16) {
    if (q0 > THR_SCORE) atomicAdd(&gh[(__float_as_uint(q0) >> 14) - BIN_OFF], 1u);
    if (q1 > THR_SCORE) atomicAdd(&gh[(__float_as_uint(q1) >> 14) - BIN_OFF], 1u);
    if (q2 > THR_SCORE) atomicAdd(&gh[(__float_as_uint(q2) >> 14) - BIN_OFF], 1u);
    if (q3 > THR_SCORE) atomicAdd(&gh[(__float_as_uint(q3) >> 14) - BIN_OFF], 1u);
  }
}

// ---------------------------------------------------------------------------
// Kernel 2: per image -- cutoff bin, per-bin base offsets, kept count from
// the prebuilt hist. Zeroes bincnt. (Unchanged from R13.)
// ---------------------------------------------------------------------------
__global__ __launch_bounds__(1024) void k_cutbase(const u32* __restrict__ hist,
                                                  u32* __restrict__ cutg,
                                                  u32* __restrict__ binbase,
                                                  u32* __restrict__ bincnt,
                                                  u32* __restrict__ keptT) {
  __shared__ u32 wsum[16];
  __shared__ int best;
  __shared__ u32 cutsh;
  int b = blockIdx.x, t = threadIdx.x;
  int lane = t & 63, wv = t >> 6;
  const u32* gh = hist + (size_t)b * NBIN;
  u32 v0 = gh[t * 4 + 0], v1 = gh[t * 4 + 1], v2 = gh[t * 4 + 2], v3 = gh[t * 4 + 3];
  u32 my = v0 + v1 + v2 + v3;
  u32 inc = my;
  for (int o = 1; o < 64; o <<= 1) {
    u32 x = __shfl_up(inc, o);
    if (lane >= o) inc += x;
  }
  if (lane == 63) wsum[wv] = inc;
  if (t == 0) best = 0;

  u32* bc = bincnt + (size_t)b * NBIN + t * 4;
  bc[0] = 0; bc[1] = 0; bc[2] = 0; bc[3] = 0;
  __syncthreads();

  u32 wpre = 0;
  for (int i = 0; i < wv; ++i) wpre += wsum[i];
  u32 total = 0;
  for (int i = 0; i < 16; ++i) total += wsum[i];
  u32 excl = wpre + (inc - my);  // prefix_excl(bin t*4)

  u32* bb = binbase + (size_t)b * NBIN + t * 4;
  u32 pi = excl;
  pi += v0; bb[0] = total - pi;
  pi += v1; bb[1] = total - pi;
  pi += v2; bb[2] = total - pi;
  pi += v3; bb[3] = total - pi;

  if (total >= K_NMS) {
    u32 lim = total - K_NMS;
    u32 p = excl;
    int cand = -1;
    if (p <= lim) cand = t * 4 + 0; p += v0;
    if (p <= lim) cand = t * 4 + 1; p += v1;
    if (p <= lim) cand = t * 4 + 2; p += v2;
    if (p <= lim) cand = t * 4 + 3; p += v3;
    if (cand >= 0) atomicMax(&best, cand);
  }
  __syncthreads();
  if (t == 0) {
    u32 c = (total >= K_NMS) ? (u32)best : 0u;
    cutsh = c;
    cutg[b] = c;
  }
  __syncthreads();
  u32 c = cutsh;
  if (t == (int)(c >> 2)) {
    u32 pe = excl;
    int r = (int)(c & 3);
    if (r > 0) pe += v0;
    if (r > 1) pe += v1;
    if (r > 2) pe += v2;
    keptT[b] = total - pe;  // count of keys with bin >= cut
  }
}

// ---------------------------------------------------------------------------
// Kernel 3: scatter kept keys into their bin's slot range in staging.
// (Unchanged from R13.)
// ---------------------------------------------------------------------------
__global__ __launch_bounds__(256) void k_scatter(const u32* __restrict__ blkcnt,
                                                 const u64* __restrict__ glist,
                                                 const u32* __restrict__ cutg,
                                                 const u32* __restrict__ binbase,
                                                 u32* __restrict__ bincnt,
                                                 u64* __restrict__ staging) {
  __shared__ u32 lcnt[128];
  __shared__ u32 mshare;
  int blk = blockIdx.x;        // 0..255
  int b = blk >> 6;            // 64 blocks per image
  int r0 = (blk & 63) * 128;   // first region of this block
  int t = threadIdx.x;
  if (t < 128) {
    u32 cc = blkcnt[b * WPI + r0 + t];
    lcnt[t] = (cc > WCAP) ? WCAP : cc;
  }
  __syncthreads();
  if (t == 0) {
    u32 m = 0;
    for (int i = 0; i < 128; ++i) m = (lcnt[i] > m) ? lcnt[i] : m;
    mshare = m;
  }
  __syncthreads();
  u32 mmax = mshare;
  u32 cut = cutg[b];
  int r = t >> 1;        // 256 threads = 128 regions x 2 slots per slab
  int k0 = t & 1;
  u32 cr = lcnt[r];
  const u64* regp = glist + ((size_t)(b * WPI + r0 + r)) * WCAP;
  for (u32 base = 0; base < mmax; base += 2) {
    u32 k = base + k0;
    if (k < cr) {
      u64 key = regp[k];
      u32 bin = (u32)(key >> 46) - BIN_OFF;
      if (bin >= cut) {
        u32 slot = binbase[(size_t)b * NBIN + bin] +
                   atomicAdd(&bincnt[(size_t)b * NBIN + bin], 1u);
        if (slot < STGN) staging[(size_t)b * STGN + slot] = key;
      }
    }
  }
}

// ---------------------------------------------------------------------------
// Kernel 4: exact in-bin rank -> global slot; decode (reference fp32 math
// exactly) into per-slot outputs; slots [T, 2048) zero-filled. (Unchanged.)
// ---------------------------------------------------------------------------
__global__ __launch_bounds__(256) void k_rankdecode(const u32* __restrict__ keptT,
                                                    const u32* __restrict__ binbase,
                                                    const u32* __restrict__ bincnt,
                                                    const u64* __restrict__ staging,
                                                    const float* __restrict__ props,
                                                    const float* __restrict__ regs,
                                                    const int* __restrict__ pH,
                                                    const int* __restrict__ pW,
                                                    float4* __restrict__ raw4,
                                                    float4* __restrict__ off4,
                                                    float* __restrict__ area,
                                                    float* __restrict__ scoref,
                                                    int* __restrict__ labeli,
                                                    int* __restrict__ flati) {
#pragma clang fp contract(off)
  int p0 = blockIdx.x * 256 + threadIdx.x;  // 0 .. B*STGN-1
  int b = p0 >> 12;
  int i = p0 & (STGN - 1);
  u32 T = keptT[b];
  if (T > STGN) T = STGN;

  if ((u32)i >= T) {
    if ((u32)i < K_NMS) {  // zero-fill empty slot i
      size_t g = (size_t)b * K_NMS + i;
      raw4[g] = make_float4(0.f, 0.f, 0.f, 0.f);
      off4[g] = make_float4(0.f, 0.f, 0.f, 0.f);
      area[g] = 0.f; scoref[g] = -1.0f; labeli[g] = 0; flati[g] = 0;
    }
    return;
  }

  u64 key = staging[(size_t)b * STGN + i];
  u32 bin = (u32)(key >> 46) - BIN_OFF;
  u32 base = binbase[(size_t)b * NBIN + bin];
  u32 cnt = bincnt[(size_t)b * NBIN + bin];
  u32 end = base + cnt;
  if (end > STGN) end = STGN;
  u32 rank = 0;
  for (u32 j = base; j < end; ++j)
    rank += (staging[(size_t)b * STGN + j] > key) ? 1u : 0u;
  u32 gslot = base + rank;
  if (gslot >= K_NMS) return;
  size_t g = (size_t)b * K_NMS + gslot;

  float Hf = (float)pH[0];
  float Wf = (float)pW[0];
  float offc = fmaxf(Hf, Wf) + 1.0f;  // 1334

  u32 flat = ~(u32)(key & 0xFFFFFFFFull);
  float sc = __uint_as_float((u32)(key >> 32));
  int n = (int)(flat / NCLS);
  int c = (int)(flat - (u32)n * NCLS);

  float4 p = ((const float4*)props)[b * N_ROI + n];
  const float4 dl = *(const float4*)(regs + ((size_t)(b * N_ROI + n)) * (NCLS * 4) + c * 4);

  float mr = fabsf(logf(16.0f / 1000.0f));
  float dx = dl.x * 0.1f;
  float dy = dl.y * 0.1f;
  float dw = fminf(fmaxf(dl.z * 0.2f, -mr), mr);
  float dh = fminf(fmaxf(dl.w * 0.2f, -mr), mr);

  float px = (p.x + p.z) * 0.5f;
  float py = (p.y + p.w) * 0.5f;
  float pw = p.z - p.x;
  float ph = p.w - p.y;

  float tx = pw * dx; float gx = px + tx;
  float ty = ph * dy; float gy = py + ty;
  float gw = pw * expf(dw);
  float gh = ph * expf(dh);
  float hx = gw * 0.5f, hy = gh * 0.5f;

  float x1 = fminf(fmaxf(gx - hx, 0.0f), Wf);
  float y1 = fminf(fmaxf(gy - hy, 0.0f), Hf);
  float x2 = fminf(fmaxf(gx + hx, 0.0f), Wf);
  float y2 = fminf(fmaxf(gy + hy, 0.0f), Hf);

  raw4[g] = make_float4(x1, y1, x2, y2);

  float off = (float)c * offc;
  float ox1 = x1 + off, oy1 = y1 + off, ox2 = x2 + off, oy2 = y2 + off;
  off4[g] = make_float4(ox1, oy1, ox2, oy2);
  area[g] = fmaxf(ox2 - ox1, 0.0f) * fmaxf(oy2 - oy1, 0.0f);
  scoref[g] = sc;
  labeli[g] = c;
  flati[g] = (int)flat;
}

// ---------------------------------------------------------------------------
// Kernel 5: suppression bitmask, triangular. (Unchanged.)
// ---------------------------------------------------------------------------
__global__ __launch_bounds__(256) void k_mask(const float4* __restrict__ off4,
                                              const float* __restrict__ area,
                                              u64* __restrict__ masks) {
#pragma clang fp contract(off)
  int wave = threadIdx.x >> 6, lane = threadIdx.x & 63;
  int R = blockIdx.x * 4 + wave;  // 0 .. B*K-1
  int b = R >> 11, i = R & (K_NMS - 1);
  const float4* bb = off4 + (size_t)b * K_NMS;
  const float* aa = area + (size_t)b * K_NMS;
  float4 bi = bb[i];
  float ai = aa[i];
  u64 my = 0;
  for (int w = i >> 6; w < 32; ++w) {
    int j = (w << 6) + lane;
    float4 bj = bb[j];
    float lx = fmaxf(bi.x, bj.x);
    float ly = fmaxf(bi.y, bj.y);
    float rx = fminf(bi.z, bj.z);
    float ry = fminf(bi.w, bj.w);
    float ww = fmaxf(rx - lx, 0.0f);
    float hh = fmaxf(ry - ly, 0.0f);
    float inter = ww * hh;
    float uni = (ai + aa[j]) - inter;
    float iou = inter / fmaxf(uni, 1e-6f);
    bool sup = (j > i) && (iou > THR_IOU);
    u64 word = __ballot(sup);
    if (lane == w) my = word;
  }
  if (lane < 32) masks[((size_t)R << 5) + lane] = my;
}

// ---------------------------------------------------------------------------
// Kernel 6: greedy scan, chunked closure + early termination. (Unchanged.)
// ---------------------------------------------------------------------------
__global__ __launch_bounds__(64, 1) void k_scanout(const u64* __restrict__ masks,
                                                   const u32* __restrict__ keptT,
                                                   const float* __restrict__ scoref,
                                                   const float4* __restrict__ raw4,
                                                   const int* __restrict__ labeli,
                                                   const int* __restrict__ flati,
                                                   float* __restrict__ out) {
  int b = blockIdx.x;
  int lane = threadIdx.x;

  u32 Tc = keptT[b];
  if (Tc > K_NMS) Tc = K_NMS;
  u64 kw = 0;
  if (lane < 32) {
    int rem = (int)Tc - (lane << 6);
    kw = (rem >= 64) ? ~0ull : ((rem > 0) ? ((1ull << rem) - 1ull) : 0ull);
  }

  const u64* mrow = masks + ((size_t)b << 16);  // b * 2048 * 32
  int myw = lane & 31;
  int half = lane >> 5;

  u64 dnext = mrow[((size_t)lane << 5) + 0];

  for (int c = 0; c < 32; ++c) {
    u64 dcur = dnext;
    if (c < 31) dnext = mrow[((size_t)((c + 1) * 64 + lane) << 5) + (c + 1)];

    const u64* rb = mrow + (((size_t)(c * 64 + half * 32)) << 5) + myw;
    u64 r0 = rb[0u << 5],  r1 = rb[1u << 5],  r2 = rb[2u << 5],  r3 = rb[3u << 5];
    u64 r4 = rb[4u << 5],  r5 = rb[5u << 5],  r6 = rb[6u << 5],  r7 = rb[7u << 5];
    u64 r8 = rb[8u << 5],  r9 = rb[9u << 5],  r10 = rb[10u << 5], r11 = rb[11u << 5];
    u64 r12 = rb[12u << 5], r13 = rb[13u << 5], r14 = rb[14u << 5], r15 = rb[15u << 5];
    u64 r16 = rb[16u << 5], r17 = rb[17u << 5], r18 = rb[18u << 5], r19 = rb[19u << 5];
    u64 r20 = rb[20u << 5], r21 = rb[21u << 5], r22 = rb[22u << 5], r23 = rb[23u << 5];
    u64 r24 = rb[24u << 5], r25 = rb[25u << 5], r26 = rb[26u << 5], r27 = rb[27u << 5];
    u64 r28 = rb[28u << 5], r29 = rb[29u << 5], r30 = rb[30u << 5], r31 = rb[31u << 5];
    asm volatile("" : "+v"(r0), "+v"(r1), "+v"(r2), "+v"(r3));
    asm volatile("" : "+v"(r4), "+v"(r5), "+v"(r6), "+v"(r7));
    asm volatile("" : "+v"(r8), "+v"(r9), "+v"(r10), "+v"(r11));
    asm volatile("" : "+v"(r12), "+v"(r13), "+v"(r14), "+v"(r15));
    asm volatile("" : "+v"(r16), "+v"(r17), "+v"(r18), "+v"(r19));
    asm volatile("" : "+v"(r20), "+v"(r21), "+v"(r22), "+v"(r23));
    asm volatile("" : "+v"(r24), "+v"(r25), "+v"(r26), "+v"(r27));
    asm volatile("" : "+v"(r28), "+v"(r29), "+v"(r30), "+v"(r31));

    u32 dlo = (u32)dcur, dhi = (u32)(dcur >> 32);
    u64 kc = ((u64)(u32)__builtin_amdgcn_readlane((int)(u32)(kw >> 32), c) << 32) |
             (u32)__builtin_amdgcn_readlane((int)(u32)kw, c);
#pragma unroll
    for (int d = 0; d < 64; ++d) {
      u64 dg = ((u64)(u32)__builtin_amdgcn_readlane((int)dhi, d) << 32) |
               (u32)__builtin_amdgcn_readlane((int)dlo, d);
      u64 on = (u64)0 - ((kc >> d) & 1ull);
      kc &= ~(dg & on);
    }

    u32 kb = half ? (u32)(kc >> 32) : (u32)kc;
#define ONB(r) ((u64)0 - (u64)((kb >> (r)) & 1u))
    u64 a0 = (r0 & ONB(0)) | (r1 & ONB(1)) | (r2 & ONB(2)) | (r3 & ONB(3)) |
             (r4 & ONB(4)) | (r5 & ONB(5)) | (r6 & ONB(6)) | (r7 & ONB(7));
    u64 a1 = (r8 & ONB(8)) | (r9 & ONB(9)) | (r10 & ONB(10)) | (r11 & ONB(11)) |
             (r12 & ONB(12)) | (r13 & ONB(13)) | (r14 & ONB(14)) | (r15 & ONB(15));
    u64 a2 = (r16 & ONB(16)) | (r17 & ONB(17)) | (r18 & ONB(18)) | (r19 & ONB(19)) |
             (r20 & ONB(20)) | (r21 & ONB(21)) | (r22 & ONB(22)) | (r23 & ONB(23));
    u64 a3 = (r24 & ONB(24)) | (r25 & ONB(25)) | (r26 & ONB(26)) | (r27 & ONB(27)) |
             (r28 & ONB(28)) | (r29 & ONB(29)) | (r30 & ONB(30)) | (r31 & ONB(31));
#undef ONB
    u64 supp = (a0 | a1) | (a2 | a3);
    supp |= __shfl_xor(supp, 32);
    kw &= ~supp;

    int fin = (lane <= c) ? __popcll(kw) : 0;
    for (int o = 32; o; o >>= 1) fin += __shfl_xor(fin, o);
    if (fin >= MAXOUT) break;
  }

  int pc = (lane < 32) ? __popcll(kw) : 0;
  int pre = pc;
  for (int o = 1; o < 64; o <<= 1) {
    int v = __shfl_up(pre, o);
    if (lane >= o) pre += v;
  }
  int excl = pre - pc;
  int total = __shfl(pre, 63);

  float* ob = out;                              // [B,100,4]
  float* os = out + B_IMG * MAXOUT * 4;         // [B,100]
  float* ol = os + B_IMG * MAXOUT;              // [B,100]
  float* oi = ol + B_IMG * MAXOUT;              // [B,100]

  if (lane < 32) {
    u64 w = kw;
    int r = excl;
    while (w) {
      int bit = __ffsll((long long)w) - 1;
      w &= w - 1;
      if (r < MAXOUT) {
        int j = (lane << 6) + bit;
        size_t g = (size_t)b * K_NMS + j;
        float4 bx = raw4[g];
        int o = b * MAXOUT + r;
        ob[o * 4 + 0] = bx.x; ob[o * 4 + 1] = bx.y;
        ob[o * 4 + 2] = bx.z; ob[o * 4 + 3] = bx.w;
        os[o] = scoref[g];
        ol[o] = (float)labeli[g];
        oi[o] = (float)flati[g];
      }
      ++r;
    }
  }
  for (int r = total + lane; r < MAXOUT; r += 64) {
    int o = b * MAXOUT + r;
    ob[o * 4 + 0] = 0.f; ob[o * 4 + 1] = 0.f; ob[o * 4 + 2] = 0.f; ob[o * 4 + 3] = 0.f;
    os[o] = 0.f;
    ol[o] = -1.0f;
    oi[o] = -1.0f;
  }
}

// ---------------------------------------------------------------------------
extern "C" void kernel_launch(void* const* d_in, const int* in_sizes, int n_in,
                              void* d_out, int out_size, void* d_ws, size_t ws_size,
                              hipStream_t stream) {
  const float* cls = (const float*)d_in[0];
  const float* regs = (const float*)d_in[1];
  const float* props = (const float*)d_in[2];
  const int* pH = (const int*)d_in[3];
  const int* pW = (const int*)d_in[4];

  char* ws = (char*)d_ws;
  size_t o = 0;
  u32* hist = (u32*)(ws + o); o += (size_t)B_IMG * NBIN * sizeof(u32);             // 64 KB (k_zero)
  u32* blkcnt = (u32*)(ws + o); o += (size_t)B_IMG * WPI * sizeof(u32);            // 128 KB
  u32* keptT = (u32*)(ws + o); o += 256;
  u32* cutg = (u32*)(ws + o); o += 256;
  u32* binbase = (u32*)(ws + o); o += (size_t)B_IMG * NBIN * sizeof(u32);          // 64 KB
  u32* bincnt = (u32*)(ws + o); o += (size_t)B_IMG * NBIN * sizeof(u32);           // 64 KB (zeroed in k_cutbase)
  u64* glist = (u64*)(ws + o); o += (size_t)B_IMG * WPI * WCAP * sizeof(u64);      // 8 MB
  u64* staging = (u64*)(ws + o); o += (size_t)B_IMG * STGN * sizeof(u64);          // 128 KB
  float4* raw4 = (float4*)(ws + o); o += (size_t)B_IMG * K_NMS * sizeof(float4);
  float4* off4 = (float4*)(ws + o); o += (size_t)B_IMG * K_NMS * sizeof(float4);
  float* area = (float*)(ws + o); o += (size_t)B_IMG * K_NMS * sizeof(float);
  float* scoref = (float*)(ws + o); o += (size_t)B_IMG * K_NMS * sizeof(float);
  int* labeli = (int*)(ws + o); o += (size_t)B_IMG * K_NMS * sizeof(int);
  int* flati = (int*)(ws + o); o += (size_t)B_IMG * K_NMS * sizeof(int);
  u64* masks = (u64*)(ws + o); o += (size_t)B_IMG * K_NMS * 32 * sizeof(u64);      // 2 MB

  int hist_words = B_IMG * NBIN;  // 16384
  k_zero<<<(hist_words + 255) / 256, 256, 0, stream>>>(hist, hist_words);
  k_score<<<B_IMG * WPI / 16, 256, 0, stream>>>(cls, blkcnt, glist, hist);
  k_cutbase<<<B_IMG, 1024, 0, stream>>>(hist, cutg, binbase, bincnt, keptT);
  k_scatter<<<256, 256, 0, stream>>>(blkcnt, glist, cutg, binbase, bincnt, staging);
  k_rankdecode<<<B_IMG * STGN / 256, 256, 0, stream>>>(keptT, binbase, bincnt, staging,
                                                       props, regs, pH, pW,
                                                       raw4, off4, area, scoref, labeli, flati);
  k_mask<<<B_IMG * K_NMS / 4, 256, 0, stream>>>(off4, area, masks);
  k_scanout<<<B_IMG, 64, 0, stream>>>(masks, keptT, scoref, raw4, labeli, flati, (float*)d_out);
}

// Round 15
// 79.899 us; speedup vs baseline: 1.1659x; 1.1630x over previous
//
#include <hip/hip_runtime.h>
#include <cstdint>
#include <cstddef>

#pragma clang fp contract(off)

typedef unsigned long long u64;
typedef unsigned int u32;

#define B_IMG 4
#define N_ROI 8192
#define NCLS 80
#define NCOL 81
#define K_NMS 2048
#define MAXOUT 100
#define THR_SCORE 0.05f
#define THR_IOU 0.5f

#define NBIN 4096
#define BIN_OFF 62771u  // (0x3D4CCCCD >> 14): bin of smallest float > 0.05f
#define WPI 8192        // per-RoI regions per image
#define WCAP 32         // max keys per RoI (hard max 19: softmax sums to 1)
#define STGN 4096       // staging capacity per image

// ---------------------------------------------------------------------------
// Kernel 1: softmax for FOUR RoIs per wave, fully interleaved (ILP hides the
// shfl/exp/div latency chain). NO hist atomics (R12-R14 lesson: ~19k global
// atomics on threshold-clustered bins cost ~15-20us; hist is built LDS-side
// in k_histcut instead). Per-RoI computation order is bit-identical to ref.
// ---------------------------------------------------------------------------
__global__ __launch_bounds__(256) void k_score(const float* __restrict__ cls,
                                               u32* __restrict__ blkcnt,
                                               u64* __restrict__ glist) {
#pragma clang fp contract(off)
  int t = threadIdx.x, wv = t >> 6, lane = t & 63;
  int wid0 = (blockIdx.x * 4 + wv) * 4;  // first of 4 RoIs for this wave

  const float* row0 = cls + (size_t)(wid0 + 0) * NCOL;
  const float* row1 = cls + (size_t)(wid0 + 1) * NCOL;
  const float* row2 = cls + (size_t)(wid0 + 2) * NCOL;
  const float* row3 = cls + (size_t)(wid0 + 3) * NCOL;
  float a0 = row0[lane], a1 = row1[lane], a2 = row2[lane], a3 = row3[lane];
  bool hi = lane < (NCOL - 64);
  float b0 = hi ? row0[64 + lane] : -1e38f;
  float b1 = hi ? row1[64 + lane] : -1e38f;
  float b2 = hi ? row2[64 + lane] : -1e38f;
  float b3 = hi ? row3[64 + lane] : -1e38f;

  float m0 = fmaxf(a0, b0), m1 = fmaxf(a1, b1), m2 = fmaxf(a2, b2), m3 = fmaxf(a3, b3);
#define MAXSTEP(o) \
  m0 = fmaxf(m0, __shfl_xor(m0, o)); m1 = fmaxf(m1, __shfl_xor(m1, o)); \
  m2 = fmaxf(m2, __shfl_xor(m2, o)); m3 = fmaxf(m3, __shfl_xor(m3, o));
  MAXSTEP(32) MAXSTEP(16) MAXSTEP(8) MAXSTEP(4) MAXSTEP(2) MAXSTEP(1)
#undef MAXSTEP

  float e0 = expf(a0 - m0), e1 = expf(a1 - m1), e2 = expf(a2 - m2), e3 = expf(a3 - m3);
  float f0 = hi ? expf(b0 - m0) : 0.0f;
  float f1 = hi ? expf(b1 - m1) : 0.0f;
  float f2 = hi ? expf(b2 - m2) : 0.0f;
  float f3 = hi ? expf(b3 - m3) : 0.0f;
  float s0 = e0 + f0, s1 = e1 + f1, s2 = e2 + f2, s3 = e3 + f3;
#define SUMSTEP(o) \
  s0 += __shfl_xor(s0, o); s1 += __shfl_xor(s1, o); \
  s2 += __shfl_xor(s2, o); s3 += __shfl_xor(s3, o);
  SUMSTEP(32) SUMSTEP(16) SUMSTEP(8) SUMSTEP(4) SUMSTEP(2) SUMSTEP(1)
#undef SUMSTEP

  float p0 = e0 / s0, p1 = e1 / s1, p2 = e2 / s2, p3 = e3 / s3;  // class=lane
  float q0 = f0 / s0, q1 = f1 / s1, q2 = f2 / s2, q3 = f3 / s3;  // class=64+lane

  u64 lm = (1ull << lane) - 1ull;
  bool lo16 = lane < 16;
  u32 cnt0, cnt1, cnt2, cnt3;

#define EMIT(R, pv, qv, CNT)                                               \
  {                                                                        \
    bool c0 = pv > THR_SCORE;                                              \
    bool c1 = lo16 && (qv > THR_SCORE);                                    \
    u64 B0 = __ballot(c0), B1 = __ballot(c1);                              \
    CNT = (u32)(__popcll(B0) + __popcll(B1));                              \
    int n = (wid0 + R) & (N_ROI - 1);                                      \
    u64* reg = glist + (size_t)(wid0 + R) * WCAP;                          \
    if (c0) {                                                              \
      u32 pos = (u32)__popcll(B0 & lm);                                    \
      if (pos < WCAP) {                                                    \
        u32 flat = (u32)(n * NCLS + lane);                                 \
        reg[pos] = ((u64)__float_as_uint(pv) << 32) | (u32)(~flat);        \
      }                                                                    \
    }                                                                      \
    if (c1) {                                                              \
      u32 pos = (u32)__popcll(B0) + (u32)__popcll(B1 & lm);                \
      if (pos < WCAP) {                                                    \
        u32 flat = (u32)(n * NCLS + 64 + lane);                            \
        reg[pos] = ((u64)__float_as_uint(qv) << 32) | (u32)(~flat);        \
      }                                                                    \
    }                                                                      \
  }

  EMIT(0, p0, q0, cnt0)
  EMIT(1, p1, q1, cnt1)
  EMIT(2, p2, q2, cnt2)
  EMIT(3, p3, q3, cnt3)
#undef EMIT

  if (lane == 0) {
    uint4 v = make_uint4(cnt0, cnt1, cnt2, cnt3);
    *(uint4*)&blkcnt[wid0] = v;  // wid0 % 4 == 0 -> 16B aligned
  }
}

// ---------------------------------------------------------------------------
// Kernel 2: per image -- LDS histogram by streaming the stored keys (proven
// R11 structure, adapted to per-RoI regions), then cutoff + binbase + keptT
// (bit-identical arithmetic) and zero global bincnt for k_scatter.
// ---------------------------------------------------------------------------
__global__ __launch_bounds__(1024) void k_histcut(const u32* __restrict__ blkcnt,
                                                  const u64* __restrict__ glist,
                                                  u32* __restrict__ cutg,
                                                  u32* __restrict__ binbase,
                                                  u32* __restrict__ bincnt,
                                                  u32* __restrict__ keptT) {
  __shared__ u32 lh[NBIN];
  __shared__ u32 wsum[16];
  __shared__ int best;
  __shared__ u32 cutsh;
  int b = blockIdx.x, t = threadIdx.x;
  int lane = t & 63, wv = t >> 6;

  for (int i = t; i < NBIN; i += 1024) lh[i] = 0;
  __syncthreads();

  // stream this image's per-RoI regions (thread t -> 8 regions)
  for (int r = t; r < WPI; r += 1024) {
    u32 cnt = blkcnt[b * WPI + r];
    if (cnt > WCAP) cnt = WCAP;
    const u64* reg = glist + ((size_t)(b * WPI + r)) * WCAP;
    for (u32 k = 0; k < cnt; ++k) {
      u64 key = reg[k];
      atomicAdd(&lh[(u32)(key >> 46) - BIN_OFF], 1u);
    }
  }
  if (t == 0) best = 0;
  __syncthreads();

  u32 v0 = lh[t * 4 + 0], v1 = lh[t * 4 + 1], v2 = lh[t * 4 + 2], v3 = lh[t * 4 + 3];
  u32 my = v0 + v1 + v2 + v3;
  u32 inc = my;
  for (int o = 1; o < 64; o <<= 1) {
    u32 x = __shfl_up(inc, o);
    if (lane >= o) inc += x;
  }
  if (lane == 63) wsum[wv] = inc;

  // zero global bincnt for this image while the scan settles
  u32* bc = bincnt + (size_t)b * NBIN + t * 4;
  bc[0] = 0; bc[1] = 0; bc[2] = 0; bc[3] = 0;
  __syncthreads();

  u32 wpre = 0;
  for (int i = 0; i < wv; ++i) wpre += wsum[i];
  u32 total = 0;
  for (int i = 0; i < 16; ++i) total += wsum[i];
  u32 excl = wpre + (inc - my);  // prefix_excl(bin t*4)

  u32* bb = binbase + (size_t)b * NBIN + t * 4;
  u32 pi = excl;
  pi += v0; bb[0] = total - pi;
  pi += v1; bb[1] = total - pi;
  pi += v2; bb[2] = total - pi;
  pi += v3; bb[3] = total - pi;

  if (total >= K_NMS) {
    u32 lim = total - K_NMS;
    u32 p = excl;
    int cand = -1;
    if (p <= lim) cand = t * 4 + 0; p += v0;
    if (p <= lim) cand = t * 4 + 1; p += v1;
    if (p <= lim) cand = t * 4 + 2; p += v2;
    if (p <= lim) cand = t * 4 + 3; p += v3;
    if (cand >= 0) atomicMax(&best, cand);
  }
  __syncthreads();
  if (t == 0) {
    u32 c = (total >= K_NMS) ? (u32)best : 0u;
    cutsh = c;
    cutg[b] = c;
  }
  __syncthreads();
  u32 c = cutsh;
  if (t == (int)(c >> 2)) {
    u32 pe = excl;
    int r = (int)(c & 3);
    if (r > 0) pe += v0;
    if (r > 1) pe += v1;
    if (r > 2) pe += v2;
    keptT[b] = total - pe;  // count of keys with bin >= cut
  }
}

// ---------------------------------------------------------------------------
// Kernel 3: scatter kept keys into their bin's slot range in staging.
// (Unchanged from R14.)
// ---------------------------------------------------------------------------
__global__ __launch_bounds__(256) void k_scatter(const u32* __restrict__ blkcnt,
                                                 const u64* __restrict__ glist,
                                                 const u32* __restrict__ cutg,
                                                 const u32* __restrict__ binbase,
                                                 u32* __restrict__ bincnt,
                                                 u64* __restrict__ staging) {
  __shared__ u32 lcnt[128];
  __shared__ u32 mshare;
  int blk = blockIdx.x;        // 0..255
  int b = blk >> 6;            // 64 blocks per image
  int r0 = (blk & 63) * 128;   // first region of this block
  int t = threadIdx.x;
  if (t < 128) {
    u32 cc = blkcnt[b * WPI + r0 + t];
    lcnt[t] = (cc > WCAP) ? WCAP : cc;
  }
  __syncthreads();
  if (t == 0) {
    u32 m = 0;
    for (int i = 0; i < 128; ++i) m = (lcnt[i] > m) ? lcnt[i] : m;
    mshare = m;
  }
  __syncthreads();
  u32 mmax = mshare;
  u32 cut = cutg[b];
  int r = t >> 1;        // 256 threads = 128 regions x 2 slots per slab
  int k0 = t & 1;
  u32 cr = lcnt[r];
  const u64* regp = glist + ((size_t)(b * WPI + r0 + r)) * WCAP;
  for (u32 base = 0; base < mmax; base += 2) {
    u32 k = base + k0;
    if (k < cr) {
      u64 key = regp[k];
      u32 bin = (u32)(key >> 46) - BIN_OFF;
      if (bin >= cut) {
        u32 slot = binbase[(size_t)b * NBIN + bin] +
                   atomicAdd(&bincnt[(size_t)b * NBIN + bin], 1u);
        if (slot < STGN) staging[(size_t)b * STGN + slot] = key;
      }
    }
  }
}

// ---------------------------------------------------------------------------
// Kernel 4: exact in-bin rank -> global slot; decode (reference fp32 math
// exactly) into per-slot outputs; slots [T, 2048) zero-filled. (Unchanged.)
// ---------------------------------------------------------------------------
__global__ __launch_bounds__(256) void k_rankdecode(const u32* __restrict__ keptT,
                                                    const u32* __restrict__ binbase,
                                                    const u32* __restrict__ bincnt,
                                                    const u64* __restrict__ staging,
                                                    const float* __restrict__ props,
                                                    const float* __restrict__ regs,
                                                    const int* __restrict__ pH,
                                                    const int* __restrict__ pW,
                                                    float4* __restrict__ raw4,
                                                    float4* __restrict__ off4,
                                                    float* __restrict__ area,
                                                    float* __restrict__ scoref,
                                                    int* __restrict__ labeli,
                                                    int* __restrict__ flati) {
#pragma clang fp contract(off)
  int p0 = blockIdx.x * 256 + threadIdx.x;  // 0 .. B*STGN-1
  int b = p0 >> 12;
  int i = p0 & (STGN - 1);
  u32 T = keptT[b];
  if (T > STGN) T = STGN;

  if ((u32)i >= T) {
    if ((u32)i < K_NMS) {  // zero-fill empty slot i
      size_t g = (size_t)b * K_NMS + i;
      raw4[g] = make_float4(0.f, 0.f, 0.f, 0.f);
      off4[g] = make_float4(0.f, 0.f, 0.f, 0.f);
      area[g] = 0.f; scoref[g] = -1.0f; labeli[g] = 0; flati[g] = 0;
    }
    return;
  }

  u64 key = staging[(size_t)b * STGN + i];
  u32 bin = (u32)(key >> 46) - BIN_OFF;
  u32 base = binbase[(size_t)b * NBIN + bin];
  u32 cnt = bincnt[(size_t)b * NBIN + bin];
  u32 end = base + cnt;
  if (end > STGN) end = STGN;
  u32 rank = 0;
  for (u32 j = base; j < end; ++j)
    rank += (staging[(size_t)b * STGN + j] > key) ? 1u : 0u;
  u32 gslot = base + rank;
  if (gslot >= K_NMS) return;
  size_t g = (size_t)b * K_NMS + gslot;

  float Hf = (float)pH[0];
  float Wf = (float)pW[0];
  float offc = fmaxf(Hf, Wf) + 1.0f;  // 1334

  u32 flat = ~(u32)(key & 0xFFFFFFFFull);
  float sc = __uint_as_float((u32)(key >> 32));
  int n = (int)(flat / NCLS);
  int c = (int)(flat - (u32)n * NCLS);

  float4 p = ((const float4*)props)[b * N_ROI + n];
  const float4 dl = *(const float4*)(regs + ((size_t)(b * N_ROI + n)) * (NCLS * 4) + c * 4);

  float mr = fabsf(logf(16.0f / 1000.0f));
  float dx = dl.x * 0.1f;
  float dy = dl.y * 0.1f;
  float dw = fminf(fmaxf(dl.z * 0.2f, -mr), mr);
  float dh = fminf(fmaxf(dl.w * 0.2f, -mr), mr);

  float px = (p.x + p.z) * 0.5f;
  float py = (p.y + p.w) * 0.5f;
  float pw = p.z - p.x;
  float ph = p.w - p.y;

  float tx = pw * dx; float gx = px + tx;
  float ty = ph * dy; float gy = py + ty;
  float gw = pw * expf(dw);
  float gh = ph * expf(dh);
  float hx = gw * 0.5f, hy = gh * 0.5f;

  float x1 = fminf(fmaxf(gx - hx, 0.0f), Wf);
  float y1 = fminf(fmaxf(gy - hy, 0.0f), Hf);
  float x2 = fminf(fmaxf(gx + hx, 0.0f), Wf);
  float y2 = fminf(fmaxf(gy + hy, 0.0f), Hf);

  raw4[g] = make_float4(x1, y1, x2, y2);

  float off = (float)c * offc;
  float ox1 = x1 + off, oy1 = y1 + off, ox2 = x2 + off, oy2 = y2 + off;
  off4[g] = make_float4(ox1, oy1, ox2, oy2);
  area[g] = fmaxf(ox2 - ox1, 0.0f) * fmaxf(oy2 - oy1, 0.0f);
  scoref[g] = sc;
  labeli[g] = c;
  flati[g] = (int)flat;
}

// ---------------------------------------------------------------------------
// Kernel 5: suppression bitmask, triangular. (Unchanged.)
// ---------------------------------------------------------------------------
__global__ __launch_bounds__(256) void k_mask(const float4* __restrict__ off4,
                                              const float* __restrict__ area,
                                              u64* __restrict__ masks) {
#pragma clang fp contract(off)
  int wave = threadIdx.x >> 6, lane = threadIdx.x & 63;
  int R = blockIdx.x * 4 + wave;  // 0 .. B*K-1
  int b = R >> 11, i = R & (K_NMS - 1);
  const float4* bb = off4 + (size_t)b * K_NMS;
  const float* aa = area + (size_t)b * K_NMS;
  float4 bi = bb[i];
  float ai = aa[i];
  u64 my = 0;
  for (int w = i >> 6; w < 32; ++w) {
    int j = (w << 6) + lane;
    float4 bj = bb[j];
    float lx = fmaxf(bi.x, bj.x);
    float ly = fmaxf(bi.y, bj.y);
    float rx = fminf(bi.z, bj.z);
    float ry = fminf(bi.w, bj.w);
    float ww = fmaxf(rx - lx, 0.0f);
    float hh = fmaxf(ry - ly, 0.0f);
    float inter = ww * hh;
    float uni = (ai + aa[j]) - inter;
    float iou = inter / fmaxf(uni, 1e-6f);
    bool sup = (j > i) && (iou > THR_IOU);
    u64 word = __ballot(sup);
    if (lane == w) my = word;
  }
  if (lane < 32) masks[((size_t)R << 5) + lane] = my;
}

// ---------------------------------------------------------------------------
// Kernel 6: greedy scan, chunked closure + early termination. (Unchanged.)
// ---------------------------------------------------------------------------
__global__ __launch_bounds__(64, 1) void k_scanout(const u64* __restrict__ masks,
                                                   const u32* __restrict__ keptT,
                                                   const float* __restrict__ scoref,
                                                   const float4* __restrict__ raw4,
                                                   const int* __restrict__ labeli,
                                                   const int* __restrict__ flati,
                                                   float* __restrict__ out) {
  int b = blockIdx.x;
  int lane = threadIdx.x;

  u32 Tc = keptT[b];
  if (Tc > K_NMS) Tc = K_NMS;
  u64 kw = 0;
  if (lane < 32) {
    int rem = (int)Tc - (lane << 6);
    kw = (rem >= 64) ? ~0ull : ((rem > 0) ? ((1ull << rem) - 1ull) : 0ull);
  }

  const u64* mrow = masks + ((size_t)b << 16);  // b * 2048 * 32
  int myw = lane & 31;
  int half = lane >> 5;

  u64 dnext = mrow[((size_t)lane << 5) + 0];

  for (int c = 0; c < 32; ++c) {
    u64 dcur = dnext;
    if (c < 31) dnext = mrow[((size_t)((c + 1) * 64 + lane) << 5) + (c + 1)];

    const u64* rb = mrow + (((size_t)(c * 64 + half * 32)) << 5) + myw;
    u64 r0 = rb[0u << 5],  r1 = rb[1u << 5],  r2 = rb[2u << 5],  r3 = rb[3u << 5];
    u64 r4 = rb[4u << 5],  r5 = rb[5u << 5],  r6 = rb[6u << 5],  r7 = rb[7u << 5];
    u64 r8 = rb[8u << 5],  r9 = rb[9u << 5],  r10 = rb[10u << 5], r11 = rb[11u << 5];
    u64 r12 = rb[12u << 5], r13 = rb[13u << 5], r14 = rb[14u << 5], r15 = rb[15u << 5];
    u64 r16 = rb[16u << 5], r17 = rb[17u << 5], r18 = rb[18u << 5], r19 = rb[19u << 5];
    u64 r20 = rb[20u << 5], r21 = rb[21u << 5], r22 = rb[22u << 5], r23 = rb[23u << 5];
    u64 r24 = rb[24u << 5], r25 = rb[25u << 5], r26 = rb[26u << 5], r27 = rb[27u << 5];
    u64 r28 = rb[28u << 5], r29 = rb[29u << 5], r30 = rb[30u << 5], r31 = rb[31u << 5];
    asm volatile("" : "+v"(r0), "+v"(r1), "+v"(r2), "+v"(r3));
    asm volatile("" : "+v"(r4), "+v"(r5), "+v"(r6), "+v"(r7));
    asm volatile("" : "+v"(r8), "+v"(r9), "+v"(r10), "+v"(r11));
    asm volatile("" : "+v"(r12), "+v"(r13), "+v"(r14), "+v"(r15));
    asm volatile("" : "+v"(r16), "+v"(r17), "+v"(r18), "+v"(r19));
    asm volatile("" : "+v"(r20), "+v"(r21), "+v"(r22), "+v"(r23));
    asm volatile("" : "+v"(r24), "+v"(r25), "+v"(r26), "+v"(r27));
    asm volatile("" : "+v"(r28), "+v"(r29), "+v"(r30), "+v"(r31));

    u32 dlo = (u32)dcur, dhi = (u32)(dcur >> 32);
    u64 kc = ((u64)(u32)__builtin_amdgcn_readlane((int)(u32)(kw >> 32), c) << 32) |
             (u32)__builtin_amdgcn_readlane((int)(u32)kw, c);
#pragma unroll
    for (int d = 0; d < 64; ++d) {
      u64 dg = ((u64)(u32)__builtin_amdgcn_readlane((int)dhi, d) << 32) |
               (u32)__builtin_amdgcn_readlane((int)dlo, d);
      u64 on = (u64)0 - ((kc >> d) & 1ull);
      kc &= ~(dg & on);
    }

    u32 kb = half ? (u32)(kc >> 32) : (u32)kc;
#define ONB(r) ((u64)0 - (u64)((kb >> (r)) & 1u))
    u64 a0 = (r0 & ONB(0)) | (r1 & ONB(1)) | (r2 & ONB(2)) | (r3 & ONB(3)) |
             (r4 & ONB(4)) | (r5 & ONB(5)) | (r6 & ONB(6)) | (r7 & ONB(7));
    u64 a1 = (r8 & ONB(8)) | (r9 & ONB(9)) | (r10 & ONB(10)) | (r11 & ONB(11)) |
             (r12 & ONB(12)) | (r13 & ONB(13)) | (r14 & ONB(14)) | (r15 & ONB(15));
    u64 a2 = (r16 & ONB(16)) | (r17 & ONB(17)) | (r18 & ONB(18)) | (r19 & ONB(19)) |
             (r20 & ONB(20)) | (r21 & ONB(21)) | (r22 & ONB(22)) | (r23 & ONB(23));
    u64 a3 = (r24 & ONB(24)) | (r25 & ONB(25)) | (r26 & ONB(26)) | (r27 & ONB(27)) |
             (r28 & ONB(28)) | (r29 & ONB(29)) | (r30 & ONB(30)) | (r31 & ONB(31));
#undef ONB
    u64 supp = (a0 | a1) | (a2 | a3);
    supp |= __shfl_xor(supp, 32);
    kw &= ~supp;

    int fin = (lane <= c) ? __popcll(kw) : 0;
    for (int o = 32; o; o >>= 1) fin += __shfl_xor(fin, o);
    if (fin >= MAXOUT) break;
  }

  int pc = (lane < 32) ? __popcll(kw) : 0;
  int pre = pc;
  for (int o = 1; o < 64; o <<= 1) {
    int v = __shfl_up(pre, o);
    if (lane >= o) pre += v;
  }
  int excl = pre - pc;
  int total = __shfl(pre, 63);

  float* ob = out;                              // [B,100,4]
  float* os = out + B_IMG * MAXOUT * 4;         // [B,100]
  float* ol = os + B_IMG * MAXOUT;              // [B,100]
  float* oi = ol + B_IMG * MAXOUT;              // [B,100]

  if (lane < 32) {
    u64 w = kw;
    int r = excl;
    while (w) {
      int bit = __ffsll((long long)w) - 1;
      w &= w - 1;
      if (r < MAXOUT) {
        int j = (lane << 6) + bit;
        size_t g = (size_t)b * K_NMS + j;
        float4 bx = raw4[g];
        int o = b * MAXOUT + r;
        ob[o * 4 + 0] = bx.x; ob[o * 4 + 1] = bx.y;
        ob[o * 4 + 2] = bx.z; ob[o * 4 + 3] = bx.w;
        os[o] = scoref[g];
        ol[o] = (float)labeli[g];
        oi[o] = (float)flati[g];
      }
      ++r;
    }
  }
  for (int r = total + lane; r < MAXOUT; r += 64) {
    int o = b * MAXOUT + r;
    ob[o * 4 + 0] = 0.f; ob[o * 4 + 1] = 0.f; ob[o * 4 + 2] = 0.f; ob[o * 4 + 3] = 0.f;
    os[o] = 0.f;
    ol[o] = -1.0f;
    oi[o] = -1.0f;
  }
}

// ---------------------------------------------------------------------------
extern "C" void kernel_launch(void* const* d_in, const int* in_sizes, int n_in,
                              void* d_out, int out_size, void* d_ws, size_t ws_size,
                              hipStream_t stream) {
  const float* cls = (const float*)d_in[0];
  const float* regs = (const float*)d_in[1];
  const float* props = (const float*)d_in[2];
  const int* pH = (const int*)d_in[3];
  const int* pW = (const int*)d_in[4];

  char* ws = (char*)d_ws;
  size_t o = 0;
  u32* blkcnt = (u32*)(ws + o); o += (size_t)B_IMG * WPI * sizeof(u32);            // 128 KB
  u32* keptT = (u32*)(ws + o); o += 256;
  u32* cutg = (u32*)(ws + o); o += 256;
  u32* binbase = (u32*)(ws + o); o += (size_t)B_IMG * NBIN * sizeof(u32);          // 64 KB
  u32* bincnt = (u32*)(ws + o); o += (size_t)B_IMG * NBIN * sizeof(u32);           // 64 KB (zeroed in k_histcut)
  u64* glist = (u64*)(ws + o); o += (size_t)B_IMG * WPI * WCAP * sizeof(u64);      // 8 MB
  u64* staging = (u64*)(ws + o); o += (size_t)B_IMG * STGN * sizeof(u64);          // 128 KB
  float4* raw4 = (float4*)(ws + o); o += (size_t)B_IMG * K_NMS * sizeof(float4);
  float4* off4 = (float4*)(ws + o); o += (size_t)B_IMG * K_NMS * sizeof(float4);
  float* area = (float*)(ws + o); o += (size_t)B_IMG * K_NMS * sizeof(float);
  float* scoref = (float*)(ws + o); o += (size_t)B_IMG * K_NMS * sizeof(float);
  int* labeli = (int*)(ws + o); o += (size_t)B_IMG * K_NMS * sizeof(int);
  int* flati = (int*)(ws + o); o += (size_t)B_IMG * K_NMS * sizeof(int);
  u64* masks = (u64*)(ws + o); o += (size_t)B_IMG * K_NMS * 32 * sizeof(u64);      // 2 MB

  k_score<<<B_IMG * WPI / 16, 256, 0, stream>>>(cls, blkcnt, glist);
  k_histcut<<<B_IMG, 1024, 0, stream>>>(blkcnt, glist, cutg, binbase, bincnt, keptT);
  k_scatter<<<256, 256, 0, stream>>>(blkcnt, glist, cutg, binbase, bincnt, staging);
  k_rankdecode<<<B_IMG * STGN / 256, 256, 0, stream>>>(keptT, binbase, bincnt, staging,
                                                       props, regs, pH, pW,
                                                       raw4, off4, area, scoref, labeli, flati);
  k_mask<<<B_IMG * K_NMS / 4, 256, 0, stream>>>(off4, area, masks);
  k_scanout<<<B_IMG, 64, 0, stream>>>(masks, keptT, scoref, raw4, labeli, flati, (float*)d_out);
}

// Round 16
// 66.382 us; speedup vs baseline: 1.4033x; 1.2036x over previous
//
#include <hip/hip_runtime.h>
#include <cstdint>
#include <cstddef>

#pragma clang fp contract(off)

typedef unsigned long long u64;
typedef unsigned int u32;

#define B_IMG 4
#define N_ROI 8192
#define NCLS 80
#define NCOL 81
#define K_NMS 2048
#define MAXOUT 100
#define THR_SCORE 0.05f
#define THR_IOU 0.5f

#define NBIN 4096
#define BIN_OFF 62771u  // (0x3D4CCCCD >> 14): bin of smallest float > 0.05f
#define RPI 2048        // wave-regions per image (4 RoIs each)
#define BLKCAP 128      // max keys per region (worst case 4*19=76)
#define STGN 4096       // staging capacity per image

// ---------------------------------------------------------------------------
// Kernel 1: softmax for FOUR RoIs per wave, fully interleaved (ILP hides the
// shfl/exp/div chain; R14-proven). Emission: all 4 RoIs' candidates go into
// ONE contiguous 128-slot region per wave (R11-proven layout -- gives
// k_histcut/k_scatter ~9-key contiguous runs instead of 2-key fragments,
// which made R15's 4-block stream latency-bound). No LDS, no barriers.
// ---------------------------------------------------------------------------
__global__ __launch_bounds__(256) void k_score(const float* __restrict__ cls,
                                               u32* __restrict__ blkcnt,
                                               u64* __restrict__ glist) {
#pragma clang fp contract(off)
  int t = threadIdx.x, wv = t >> 6, lane = t & 63;
  int wreg = blockIdx.x * 4 + wv;  // wave-region id: 0 .. B*RPI-1
  int wid0 = wreg * 4;             // first of 4 RoIs

  const float* row0 = cls + (size_t)(wid0 + 0) * NCOL;
  const float* row1 = cls + (size_t)(wid0 + 1) * NCOL;
  const float* row2 = cls + (size_t)(wid0 + 2) * NCOL;
  const float* row3 = cls + (size_t)(wid0 + 3) * NCOL;
  float a0 = row0[lane], a1 = row1[lane], a2 = row2[lane], a3 = row3[lane];
  bool hi = lane < (NCOL - 64);
  float b0 = hi ? row0[64 + lane] : -1e38f;
  float b1 = hi ? row1[64 + lane] : -1e38f;
  float b2 = hi ? row2[64 + lane] : -1e38f;
  float b3 = hi ? row3[64 + lane] : -1e38f;

  float m0 = fmaxf(a0, b0), m1 = fmaxf(a1, b1), m2 = fmaxf(a2, b2), m3 = fmaxf(a3, b3);
#define MAXSTEP(o) \
  m0 = fmaxf(m0, __shfl_xor(m0, o)); m1 = fmaxf(m1, __shfl_xor(m1, o)); \
  m2 = fmaxf(m2, __shfl_xor(m2, o)); m3 = fmaxf(m3, __shfl_xor(m3, o));
  MAXSTEP(32) MAXSTEP(16) MAXSTEP(8) MAXSTEP(4) MAXSTEP(2) MAXSTEP(1)
#undef MAXSTEP

  float e0 = expf(a0 - m0), e1 = expf(a1 - m1), e2 = expf(a2 - m2), e3 = expf(a3 - m3);
  float f0 = hi ? expf(b0 - m0) : 0.0f;
  float f1 = hi ? expf(b1 - m1) : 0.0f;
  float f2 = hi ? expf(b2 - m2) : 0.0f;
  float f3 = hi ? expf(b3 - m3) : 0.0f;
  float s0 = e0 + f0, s1 = e1 + f1, s2 = e2 + f2, s3 = e3 + f3;
#define SUMSTEP(o) \
  s0 += __shfl_xor(s0, o); s1 += __shfl_xor(s1, o); \
  s2 += __shfl_xor(s2, o); s3 += __shfl_xor(s3, o);
  SUMSTEP(32) SUMSTEP(16) SUMSTEP(8) SUMSTEP(4) SUMSTEP(2) SUMSTEP(1)
#undef SUMSTEP

  float p0 = e0 / s0, p1 = e1 / s1, p2 = e2 / s2, p3 = e3 / s3;  // class=lane
  float q0 = f0 / s0, q1 = f1 / s1, q2 = f2 / s2, q3 = f3 / s3;  // class=64+lane

  u64 lm = (1ull << lane) - 1ull;
  bool lo16 = lane < 16;
  u32 base = 0;
  u64* reg = glist + (size_t)wreg * BLKCAP;

#define EMIT(R, pv, qv)                                                    \
  {                                                                        \
    bool c0 = pv > THR_SCORE;                                              \
    bool c1 = lo16 && (qv > THR_SCORE);                                    \
    u64 B0 = __ballot(c0), B1 = __ballot(c1);                              \
    int n = (wid0 + R) & (N_ROI - 1);                                      \
    if (c0) {                                                              \
      u32 pos = base + (u32)__popcll(B0 & lm);                             \
      if (pos < BLKCAP) {                                                  \
        u32 flat = (u32)(n * NCLS + lane);                                 \
        reg[pos] = ((u64)__float_as_uint(pv) << 32) | (u32)(~flat);        \
      }                                                                    \
    }                                                                      \
    if (c1) {                                                              \
      u32 pos = base + (u32)__popcll(B0) + (u32)__popcll(B1 & lm);         \
      if (pos < BLKCAP) {                                                  \
        u32 flat = (u32)(n * NCLS + 64 + lane);                            \
        reg[pos] = ((u64)__float_as_uint(qv) << 32) | (u32)(~flat);        \
      }                                                                    \
    }                                                                      \
    base += (u32)(__popcll(B0) + __popcll(B1));                            \
  }

  EMIT(0, p0, q0)
  EMIT(1, p1, q1)
  EMIT(2, p2, q2)
  EMIT(3, p3, q3)
#undef EMIT

  if (lane == 0) blkcnt[wreg] = base;
}

// ---------------------------------------------------------------------------
// Kernel 2: per image -- LDS histogram by streaming regions (R11-proven:
// 2048 regions x ~9.4 contiguous keys), then cutoff + binbase + keptT
// (bit-identical arithmetic); zeroes global bincnt for k_scatter.
// ---------------------------------------------------------------------------
__global__ __launch_bounds__(1024) void k_histcut(const u32* __restrict__ blkcnt,
                                                  const u64* __restrict__ glist,
                                                  u32* __restrict__ cutg,
                                                  u32* __restrict__ binbase,
                                                  u32* __restrict__ bincnt,
                                                  u32* __restrict__ keptT) {
  __shared__ u32 lh[NBIN];
  __shared__ u32 wsum[16];
  __shared__ int best;
  __shared__ u32 cutsh;
  int b = blockIdx.x, t = threadIdx.x;
  int lane = t & 63, wv = t >> 6;

  for (int i = t; i < NBIN; i += 1024) lh[i] = 0;
  __syncthreads();

  // stream this image's regions directly (thread t -> regions t, t+1024)
  for (int r = t; r < RPI; r += 1024) {
    u32 cnt = blkcnt[b * RPI + r];
    if (cnt > BLKCAP) cnt = BLKCAP;
    const u64* reg = glist + ((size_t)(b * RPI + r)) * BLKCAP;
    for (u32 k = 0; k < cnt; ++k) {
      u64 key = reg[k];
      atomicAdd(&lh[(u32)(key >> 46) - BIN_OFF], 1u);
    }
  }
  if (t == 0) best = 0;
  __syncthreads();

  u32 v0 = lh[t * 4 + 0], v1 = lh[t * 4 + 1], v2 = lh[t * 4 + 2], v3 = lh[t * 4 + 3];
  u32 my = v0 + v1 + v2 + v3;
  u32 inc = my;
  for (int o = 1; o < 64; o <<= 1) {
    u32 x = __shfl_up(inc, o);
    if (lane >= o) inc += x;
  }
  if (lane == 63) wsum[wv] = inc;

  // zero global bincnt for this image while the scan settles
  u32* bc = bincnt + (size_t)b * NBIN + t * 4;
  bc[0] = 0; bc[1] = 0; bc[2] = 0; bc[3] = 0;
  __syncthreads();

  u32 wpre = 0;
  for (int i = 0; i < wv; ++i) wpre += wsum[i];
  u32 total = 0;
  for (int i = 0; i < 16; ++i) total += wsum[i];
  u32 excl = wpre + (inc - my);  // prefix_excl(bin t*4)

  u32* bb = binbase + (size_t)b * NBIN + t * 4;
  u32 pi = excl;
  pi += v0; bb[0] = total - pi;
  pi += v1; bb[1] = total - pi;
  pi += v2; bb[2] = total - pi;
  pi += v3; bb[3] = total - pi;

  if (total >= K_NMS) {
    u32 lim = total - K_NMS;
    u32 p = excl;
    int cand = -1;
    if (p <= lim) cand = t * 4 + 0; p += v0;
    if (p <= lim) cand = t * 4 + 1; p += v1;
    if (p <= lim) cand = t * 4 + 2; p += v2;
    if (p <= lim) cand = t * 4 + 3; p += v3;
    if (cand >= 0) atomicMax(&best, cand);
  }
  __syncthreads();
  if (t == 0) {
    u32 c = (total >= K_NMS) ? (u32)best : 0u;
    cutsh = c;
    cutg[b] = c;
  }
  __syncthreads();
  u32 c = cutsh;
  if (t == (int)(c >> 2)) {
    u32 pe = excl;
    int r = (int)(c & 3);
    if (r > 0) pe += v0;
    if (r > 1) pe += v1;
    if (r > 2) pe += v2;
    keptT[b] = total - pe;  // count of keys with bin >= cut
  }
}

// ---------------------------------------------------------------------------
// Kernel 3: scatter kept keys into their bin's slot range in staging.
// 256 blocks x 32 regions; slab loop bounded by max region count (typ <=24).
// ---------------------------------------------------------------------------
__global__ __launch_bounds__(256) void k_scatter(const u32* __restrict__ blkcnt,
                                                 const u64* __restrict__ glist,
                                                 const u32* __restrict__ cutg,
                                                 const u32* __restrict__ binbase,
                                                 u32* __restrict__ bincnt,
                                                 u64* __restrict__ staging) {
  __shared__ u32 lcnt[32];
  __shared__ u32 mshare;
  int blk = blockIdx.x;      // 0..255
  int b = blk >> 6;          // 64 blocks per image
  int r0 = (blk & 63) * 32;  // first region of this block
  int t = threadIdx.x;
  if (t < 32) {
    u32 cc = blkcnt[b * RPI + r0 + t];
    lcnt[t] = (cc > BLKCAP) ? BLKCAP : cc;
  }
  __syncthreads();
  if (t == 0) {
    u32 m = 0;
    for (int i = 0; i < 32; ++i) m = (lcnt[i] > m) ? lcnt[i] : m;
    mshare = m;
  }
  __syncthreads();
  u32 mmax = mshare;
  u32 cut = cutg[b];
  int r = t >> 3;        // 256 threads = 32 regions x 8 slots per slab
  int k0 = t & 7;
  u32 cr = lcnt[r];
  const u64* regp = glist + ((size_t)(b * RPI + r0 + r)) * BLKCAP;
  for (u32 base = 0; base < mmax; base += 8) {
    u32 k = base + k0;
    if (k < cr) {
      u64 key = regp[k];
      u32 bin = (u32)(key >> 46) - BIN_OFF;
      if (bin >= cut) {
        u32 slot = binbase[(size_t)b * NBIN + bin] +
                   atomicAdd(&bincnt[(size_t)b * NBIN + bin], 1u);
        if (slot < STGN) staging[(size_t)b * STGN + slot] = key;
      }
    }
  }
}

// ---------------------------------------------------------------------------
// Kernel 4: exact in-bin rank -> global slot; decode (reference fp32 math
// exactly) into per-slot outputs; slots [T, 2048) zero-filled. (Unchanged.)
// ---------------------------------------------------------------------------
__global__ __launch_bounds__(256) void k_rankdecode(const u32* __restrict__ keptT,
                                                    const u32* __restrict__ binbase,
                                                    const u32* __restrict__ bincnt,
                                                    const u64* __restrict__ staging,
                                                    const float* __restrict__ props,
                                                    const float* __restrict__ regs,
                                                    const int* __restrict__ pH,
                                                    const int* __restrict__ pW,
                                                    float4* __restrict__ raw4,
                                                    float4* __restrict__ off4,
                                                    float* __restrict__ area,
                                                    float* __restrict__ scoref,
                                                    int* __restrict__ labeli,
                                                    int* __restrict__ flati) {
#pragma clang fp contract(off)
  int p0 = blockIdx.x * 256 + threadIdx.x;  // 0 .. B*STGN-1
  int b = p0 >> 12;
  int i = p0 & (STGN - 1);
  u32 T = keptT[b];
  if (T > STGN) T = STGN;

  if ((u32)i >= T) {
    if ((u32)i < K_NMS) {  // zero-fill empty slot i
      size_t g = (size_t)b * K_NMS + i;
      raw4[g] = make_float4(0.f, 0.f, 0.f, 0.f);
      off4[g] = make_float4(0.f, 0.f, 0.f, 0.f);
      area[g] = 0.f; scoref[g] = -1.0f; labeli[g] = 0; flati[g] = 0;
    }
    return;
  }

  u64 key = staging[(size_t)b * STGN + i];
  u32 bin = (u32)(key >> 46) - BIN_OFF;
  u32 base = binbase[(size_t)b * NBIN + bin];
  u32 cnt = bincnt[(size_t)b * NBIN + bin];
  u32 end = base + cnt;
  if (end > STGN) end = STGN;
  u32 rank = 0;
  for (u32 j = base; j < end; ++j)
    rank += (staging[(size_t)b * STGN + j] > key) ? 1u : 0u;
  u32 gslot = base + rank;
  if (gslot >= K_NMS) return;
  size_t g = (size_t)b * K_NMS + gslot;

  float Hf = (float)pH[0];
  float Wf = (float)pW[0];
  float offc = fmaxf(Hf, Wf) + 1.0f;  // 1334

  u32 flat = ~(u32)(key & 0xFFFFFFFFull);
  float sc = __uint_as_float((u32)(key >> 32));
  int n = (int)(flat / NCLS);
  int c = (int)(flat - (u32)n * NCLS);

  float4 p = ((const float4*)props)[b * N_ROI + n];
  const float4 dl = *(const float4*)(regs + ((size_t)(b * N_ROI + n)) * (NCLS * 4) + c * 4);

  float mr = fabsf(logf(16.0f / 1000.0f));
  float dx = dl.x * 0.1f;
  float dy = dl.y * 0.1f;
  float dw = fminf(fmaxf(dl.z * 0.2f, -mr), mr);
  float dh = fminf(fmaxf(dl.w * 0.2f, -mr), mr);

  float px = (p.x + p.z) * 0.5f;
  float py = (p.y + p.w) * 0.5f;
  float pw = p.z - p.x;
  float ph = p.w - p.y;

  float tx = pw * dx; float gx = px + tx;
  float ty = ph * dy; float gy = py + ty;
  float gw = pw * expf(dw);
  float gh = ph * expf(dh);
  float hx = gw * 0.5f, hy = gh * 0.5f;

  float x1 = fminf(fmaxf(gx - hx, 0.0f), Wf);
  float y1 = fminf(fmaxf(gy - hy, 0.0f), Hf);
  float x2 = fminf(fmaxf(gx + hx, 0.0f), Wf);
  float y2 = fminf(fmaxf(gy + hy, 0.0f), Hf);

  raw4[g] = make_float4(x1, y1, x2, y2);

  float off = (float)c * offc;
  float ox1 = x1 + off, oy1 = y1 + off, ox2 = x2 + off, oy2 = y2 + off;
  off4[g] = make_float4(ox1, oy1, ox2, oy2);
  area[g] = fmaxf(ox2 - ox1, 0.0f) * fmaxf(oy2 - oy1, 0.0f);
  scoref[g] = sc;
  labeli[g] = c;
  flati[g] = (int)flat;
}

// ---------------------------------------------------------------------------
// Kernel 5: suppression bitmask, triangular. (Unchanged.)
// ---------------------------------------------------------------------------
__global__ __launch_bounds__(256) void k_mask(const float4* __restrict__ off4,
                                              const float* __restrict__ area,
                                              u64* __restrict__ masks) {
#pragma clang fp contract(off)
  int wave = threadIdx.x >> 6, lane = threadIdx.x & 63;
  int R = blockIdx.x * 4 + wave;  // 0 .. B*K-1
  int b = R >> 11, i = R & (K_NMS - 1);
  const float4* bb = off4 + (size_t)b * K_NMS;
  const float* aa = area + (size_t)b * K_NMS;
  float4 bi = bb[i];
  float ai = aa[i];
  u64 my = 0;
  for (int w = i >> 6; w < 32; ++w) {
    int j = (w << 6) + lane;
    float4 bj = bb[j];
    float lx = fmaxf(bi.x, bj.x);
    float ly = fmaxf(bi.y, bj.y);
    float rx = fminf(bi.z, bj.z);
    float ry = fminf(bi.w, bj.w);
    float ww = fmaxf(rx - lx, 0.0f);
    float hh = fmaxf(ry - ly, 0.0f);
    float inter = ww * hh;
    float uni = (ai + aa[j]) - inter;
    float iou = inter / fmaxf(uni, 1e-6f);
    bool sup = (j > i) && (iou > THR_IOU);
    u64 word = __ballot(sup);
    if (lane == w) my = word;
  }
  if (lane < 32) masks[((size_t)R << 5) + lane] = my;
}

// ---------------------------------------------------------------------------
// Kernel 6: greedy scan, chunked closure + early termination. (Unchanged.)
// ---------------------------------------------------------------------------
__global__ __launch_bounds__(64, 1) void k_scanout(const u64* __restrict__ masks,
                                                   const u32* __restrict__ keptT,
                                                   const float* __restrict__ scoref,
                                                   const float4* __restrict__ raw4,
                                                   const int* __restrict__ labeli,
                                                   const int* __restrict__ flati,
                                                   float* __restrict__ out) {
  int b = blockIdx.x;
  int lane = threadIdx.x;

  u32 Tc = keptT[b];
  if (Tc > K_NMS) Tc = K_NMS;
  u64 kw = 0;
  if (lane < 32) {
    int rem = (int)Tc - (lane << 6);
    kw = (rem >= 64) ? ~0ull : ((rem > 0) ? ((1ull << rem) - 1ull) : 0ull);
  }

  const u64* mrow = masks + ((size_t)b << 16);  // b * 2048 * 32
  int myw = lane & 31;
  int half = lane >> 5;

  u64 dnext = mrow[((size_t)lane << 5) + 0];

  for (int c = 0; c < 32; ++c) {
    u64 dcur = dnext;
    if (c < 31) dnext = mrow[((size_t)((c + 1) * 64 + lane) << 5) + (c + 1)];

    const u64* rb = mrow + (((size_t)(c * 64 + half * 32)) << 5) + myw;
    u64 r0 = rb[0u << 5],  r1 = rb[1u << 5],  r2 = rb[2u << 5],  r3 = rb[3u << 5];
    u64 r4 = rb[4u << 5],  r5 = rb[5u << 5],  r6 = rb[6u << 5],  r7 = rb[7u << 5];
    u64 r8 = rb[8u << 5],  r9 = rb[9u << 5],  r10 = rb[10u << 5], r11 = rb[11u << 5];
    u64 r12 = rb[12u << 5], r13 = rb[13u << 5], r14 = rb[14u << 5], r15 = rb[15u << 5];
    u64 r16 = rb[16u << 5], r17 = rb[17u << 5], r18 = rb[18u << 5], r19 = rb[19u << 5];
    u64 r20 = rb[20u << 5], r21 = rb[21u << 5], r22 = rb[22u << 5], r23 = rb[23u << 5];
    u64 r24 = rb[24u << 5], r25 = rb[25u << 5], r26 = rb[26u << 5], r27 = rb[27u << 5];
    u64 r28 = rb[28u << 5], r29 = rb[29u << 5], r30 = rb[30u << 5], r31 = rb[31u << 5];
    asm volatile("" : "+v"(r0), "+v"(r1), "+v"(r2), "+v"(r3));
    asm volatile("" : "+v"(r4), "+v"(r5), "+v"(r6), "+v"(r7));
    asm volatile("" : "+v"(r8), "+v"(r9), "+v"(r10), "+v"(r11));
    asm volatile("" : "+v"(r12), "+v"(r13), "+v"(r14), "+v"(r15));
    asm volatile("" : "+v"(r16), "+v"(r17), "+v"(r18), "+v"(r19));
    asm volatile("" : "+v"(r20), "+v"(r21), "+v"(r22), "+v"(r23));
    asm volatile("" : "+v"(r24), "+v"(r25), "+v"(r26), "+v"(r27));
    asm volatile("" : "+v"(r28), "+v"(r29), "+v"(r30), "+v"(r31));

    u32 dlo = (u32)dcur, dhi = (u32)(dcur >> 32);
    u64 kc = ((u64)(u32)__builtin_amdgcn_readlane((int)(u32)(kw >> 32), c) << 32) |
             (u32)__builtin_amdgcn_readlane((int)(u32)kw, c);
#pragma unroll
    for (int d = 0; d < 64; ++d) {
      u64 dg = ((u64)(u32)__builtin_amdgcn_readlane((int)dhi, d) << 32) |
               (u32)__builtin_amdgcn_readlane((int)dlo, d);
      u64 on = (u64)0 - ((kc >> d) & 1ull);
      kc &= ~(dg & on);
    }

    u32 kb = half ? (u32)(kc >> 32) : (u32)kc;
#define ONB(r) ((u64)0 - (u64)((kb >> (r)) & 1u))
    u64 a0 = (r0 & ONB(0)) | (r1 & ONB(1)) | (r2 & ONB(2)) | (r3 & ONB(3)) |
             (r4 & ONB(4)) | (r5 & ONB(5)) | (r6 & ONB(6)) | (r7 & ONB(7));
    u64 a1 = (r8 & ONB(8)) | (r9 & ONB(9)) | (r10 & ONB(10)) | (r11 & ONB(11)) |
             (r12 & ONB(12)) | (r13 & ONB(13)) | (r14 & ONB(14)) | (r15 & ONB(15));
    u64 a2 = (r16 & ONB(16)) | (r17 & ONB(17)) | (r18 & ONB(18)) | (r19 & ONB(19)) |
             (r20 & ONB(20)) | (r21 & ONB(21)) | (r22 & ONB(22)) | (r23 & ONB(23));
    u64 a3 = (r24 & ONB(24)) | (r25 & ONB(25)) | (r26 & ONB(26)) | (r27 & ONB(27)) |
             (r28 & ONB(28)) | (r29 & ONB(29)) | (r30 & ONB(30)) | (r31 & ONB(31));
#undef ONB
    u64 supp = (a0 | a1) | (a2 | a3);
    supp |= __shfl_xor(supp, 32);
    kw &= ~supp;

    int fin = (lane <= c) ? __popcll(kw) : 0;
    for (int o = 32; o; o >>= 1) fin += __shfl_xor(fin, o);
    if (fin >= MAXOUT) break;
  }

  int pc = (lane < 32) ? __popcll(kw) : 0;
  int pre = pc;
  for (int o = 1; o < 64; o <<= 1) {
    int v = __shfl_up(pre, o);
    if (lane >= o) pre += v;
  }
  int excl = pre - pc;
  int total = __shfl(pre, 63);

  float* ob = out;                              // [B,100,4]
  float* os = out + B_IMG * MAXOUT * 4;         // [B,100]
  float* ol = os + B_IMG * MAXOUT;              // [B,100]
  float* oi = ol + B_IMG * MAXOUT;              // [B,100]

  if (lane < 32) {
    u64 w = kw;
    int r = excl;
    while (w) {
      int bit = __ffsll((long long)w) - 1;
      w &= w - 1;
      if (r < MAXOUT) {
        int j = (lane << 6) + bit;
        size_t g = (size_t)b * K_NMS + j;
        float4 bx = raw4[g];
        int o = b * MAXOUT + r;
        ob[o * 4 + 0] = bx.x; ob[o * 4 + 1] = bx.y;
        ob[o * 4 + 2] = bx.z; ob[o * 4 + 3] = bx.w;
        os[o] = scoref[g];
        ol[o] = (float)labeli[g];
        oi[o] = (float)flati[g];
      }
      ++r;
    }
  }
  for (int r = total + lane; r < MAXOUT; r += 64) {
    int o = b * MAXOUT + r;
    ob[o * 4 + 0] = 0.f; ob[o * 4 + 1] = 0.f; ob[o * 4 + 2] = 0.f; ob[o * 4 + 3] = 0.f;
    os[o] = 0.f;
    ol[o] = -1.0f;
    oi[o] = -1.0f;
  }
}

// ---------------------------------------------------------------------------
extern "C" void kernel_launch(void* const* d_in, const int* in_sizes, int n_in,
                              void* d_out, int out_size, void* d_ws, size_t ws_size,
                              hipStream_t stream) {
  const float* cls = (const float*)d_in[0];
  const float* regs = (const float*)d_in[1];
  const float* props = (const float*)d_in[2];
  const int* pH = (const int*)d_in[3];
  const int* pW = (const int*)d_in[4];

  char* ws = (char*)d_ws;
  size_t o = 0;
  u32* blkcnt = (u32*)(ws + o); o += (size_t)B_IMG * RPI * sizeof(u32);            // 32 KB
  u32* keptT = (u32*)(ws + o); o += 256;
  u32* cutg = (u32*)(ws + o); o += 256;
  u32* binbase = (u32*)(ws + o); o += (size_t)B_IMG * NBIN * sizeof(u32);          // 64 KB
  u32* bincnt = (u32*)(ws + o); o += (size_t)B_IMG * NBIN * sizeof(u32);           // 64 KB (zeroed in k_histcut)
  u64* glist = (u64*)(ws + o); o += (size_t)B_IMG * RPI * BLKCAP * sizeof(u64);    // 8 MB
  u64* staging = (u64*)(ws + o); o += (size_t)B_IMG * STGN * sizeof(u64);          // 128 KB
  float4* raw4 = (float4*)(ws + o); o += (size_t)B_IMG * K_NMS * sizeof(float4);
  float4* off4 = (float4*)(ws + o); o += (size_t)B_IMG * K_NMS * sizeof(float4);
  float* area = (float*)(ws + o); o += (size_t)B_IMG * K_NMS * sizeof(float);
  float* scoref = (float*)(ws + o); o += (size_t)B_IMG * K_NMS * sizeof(float);
  int* labeli = (int*)(ws + o); o += (size_t)B_IMG * K_NMS * sizeof(int);
  int* flati = (int*)(ws + o); o += (size_t)B_IMG * K_NMS * sizeof(int);
  u64* masks = (u64*)(ws + o); o += (size_t)B_IMG * K_NMS * 32 * sizeof(u64);      // 2 MB

  k_score<<<B_IMG * RPI / 4, 256, 0, stream>>>(cls, blkcnt, glist);
  k_histcut<<<B_IMG, 1024, 0, stream>>>(blkcnt, glist, cutg, binbase, bincnt, keptT);
  k_scatter<<<256, 256, 0, stream>>>(blkcnt, glist, cutg, binbase, bincnt, staging);
  k_rankdecode<<<B_IMG * STGN / 256, 256, 0, stream>>>(keptT, binbase, bincnt, staging,
                                                       props, regs, pH, pW,
                                                       raw4, off4, area, scoref, labeli, flati);
  k_mask<<<B_IMG * K_NMS / 4, 256, 0, stream>>>(off4, area, masks);
  k_scanout<<<B_IMG, 64, 0, stream>>>(masks, keptT, scoref, raw4, labeli, flati, (float*)d_out);
}